// Round 7
// baseline (426.172 us; speedup 1.0000x reference)
//
#include <hip/hip_runtime.h>
#include <hip/hip_bf16.h>

typedef int i32x4 __attribute__((ext_vector_type(4)));
typedef unsigned int u32;
typedef long long ll;

// async 16B global->LDS copy. LDS dest = wave-uniform base + lane*16.
__device__ __forceinline__ void load_lds16(const void* g, void* l) {
  __builtin_amdgcn_global_load_lds(
      (const __attribute__((address_space(1))) u32*)g,
      (__attribute__((address_space(3))) u32*)l, 16, 0, 0);
}

// ---------------------------------------------------------------------------
// prep_all: fused weight-pack + weight-sums + input quantize/im2col.
// Grid partition: [0,4096) quant0 ; [4096,6144) packing ; [6144,6189) sums.
//   w0q : i8 [ch2][mf12][quad4][col16][e16]; k=ch*64+q*16+e, k<75 ->(ci=k/25,tap=k%25)
//   wNp : i8 [tap25][ch3][mf(M/16)][quad4][col16][e16]; ci = ch*64+q*16+e
//   patch: i8 [pix][128] im2col (value-128; conv-pad = -128)
//   zbuf : 0x80 fill (B-pad reads give value-128 uniformly)
// ---------------------------------------------------------------------------
template <int MF>
__device__ __forceinline__ void pack_i8(int j, const float* wsrc, signed char* wdst) {
  int e = j & 15, col = (j >> 4) & 15, q = (j >> 8) & 3, t = j >> 10;
  int mf = t % MF; t /= MF; int ch = t % 3; int tap = t / 3;
  int oc = mf * 16 + col, ci = ch * 64 + q * 16 + e;
  wdst[j] = (signed char)(int)rintf(wsrc[(oc * 192 + ci) * 25 + tap]);
}

__global__ __launch_bounds__(256) void prep_all(
    const float* __restrict__ x,
    const float* __restrict__ w0, const float* __restrict__ w1,
    const float* __restrict__ w2, const float* __restrict__ w3,
    signed char* __restrict__ w0q, signed char* __restrict__ w1p,
    signed char* __restrict__ w2p, signed char* __restrict__ w3p,
    signed char* __restrict__ zbuf, signed char* __restrict__ patch,
    int* __restrict__ totw0, int* __restrict__ totw1,
    int* __restrict__ totw2, int* __restrict__ totw3)
{
  const int blk = blockIdx.x;
  const int tid = threadIdx.x;

  if (blk < 4096) {
    // ---- quantize + im2col ----
    __shared__ signed char ilds[3][5][132];
    const int oxblk = blk & 3;
    const int oy = (blk >> 2) & 255;
    const int b = blk >> 10;
    const int oxbase = oxblk * 64;
    for (int i = tid; i < 3 * 5 * 131; i += 256) {
      int c = i % 131; int t = i / 131; int r = t % 5; int ci = t / 5;
      int iy = 2 * oy - 2 + r;
      int ix = 2 * oxbase - 2 + c;
      int v = -128;
      if ((unsigned)iy < 512u && (unsigned)ix < 512u) {
        float xv = rintf(x[((b * 3 + ci) * 512 + iy) * 512 + ix] * 256.0f);
        xv = fminf(fmaxf(xv, 0.0f), 255.0f);
        v = (int)xv - 128;
      }
      ilds[ci][r][c] = (signed char)v;
    }
    __syncthreads();
    const int px = tid >> 2, part = tid & 3;
    const int xbase = 2 * px;
    u32 res[8];
    #pragma unroll
    for (int wd = 0; wd < 8; wd++) {
      u32 v = 0;
      #pragma unroll
      for (int bb = 0; bb < 4; bb++) {
        int k = part * 32 + wd * 4 + bb;
        u32 byte = 0;
        if (k < 75) {
          int ci = k / 25, rem = k - ci * 25, ky = rem / 5, kx = rem - ky * 5;
          byte = (u32)(unsigned char)ilds[ci][ky][xbase + kx];
        }
        v |= byte << (8 * bb);
      }
      res[wd] = v;
    }
    size_t base = ((size_t)((b * 256 + oy) * 256 + oxbase + px)) * 128 + part * 32;
    *(uint4*)(patch + base)      = make_uint4(res[0], res[1], res[2], res[3]);
    *(uint4*)(patch + base + 16) = make_uint4(res[4], res[5], res[6], res[7]);
  } else if (blk < 6144) {
    // ---- weight packing ----
    if (blk == 4096 && tid < 128)
      ((unsigned long long*)zbuf)[tid] = 0x8080808080808080ULL;
    const int R0 = 24576;                  // layer0, K padded to 128
    const int R1 = 921600;                 // 192-oc layers
    const int R3 = 1536000;                // 320-oc layer
    const int total = R0 + 2 * R1 + R3;
    for (int i = (blk - 4096) * 256 + tid; i < total; i += 2048 * 256) {
      if (i < R0) {
        int e = i & 15, col = (i >> 4) & 15, q = (i >> 8) & 3, t = i >> 10;
        int mf = t % 12, ch = t / 12;
        int k = ch * 64 + q * 16 + e;
        signed char v = 0;
        if (k < 75) {
          int ci = k / 25, tap = k - ci * 25;
          v = (signed char)(int)rintf(w0[((mf * 16 + col) * 3 + ci) * 25 + tap]);
        }
        w0q[i] = v;
      } else if (i < R0 + R1) {
        pack_i8<12>(i - R0, w1, w1p);
      } else if (i < R0 + 2 * R1) {
        pack_i8<12>(i - R0 - R1, w2, w2p);
      } else {
        pack_i8<20>(i - R0 - 2 * R1, w3, w3p);
      }
    }
  } else {
    // ---- totw sums (totw* pre-zeroed by memset) ----
    int t = (blk - 6144) * 256 + tid;
    if (t < 704 * 16) {
      int oc = t >> 4, q = t & 15;
      const float* ws; int* tot; int o = oc;
      if (oc < 192)      { ws = w1; tot = totw1; }
      else if (oc < 384) { ws = w2; tot = totw2; o = oc - 192; }
      else               { ws = w3; tot = totw3; o = oc - 384; }
      const float* p = ws + (size_t)o * 4800 + q * 300;
      int s = 0;
      #pragma unroll 4
      for (int j = 0; j < 300; j++) s += (int)rintf(p[j]);
      atomicAdd(&tot[o], s);
    } else {
      int oc = t - 704 * 16;
      if (oc < 192) {
        const float* p = w0 + (size_t)oc * 75;
        int s = 0;
        #pragma unroll 5
        for (int j = 0; j < 75; j++) s += (int)rintf(p[j]);
        totw0[oc] = s;
      }
    }
  }
}

// ---------------------------------------------------------------------------
// convP: layer0 patch-GEMM. M=192 (3 waves), N=64 px/block, K=128 (2 steps).
// A-frags global->VGPR once; B double-buffered LDS, one barrier per step.
// ---------------------------------------------------------------------------
__global__ __launch_bounds__(192, 3) void convP(
    const signed char* __restrict__ patch, const signed char* __restrict__ wq,
    const float* __restrict__ bias, const float* __restrict__ mulv,
    const int* __restrict__ totw,
    const int* __restrict__ reluP, const int* __restrict__ mdP,
    unsigned char* __restrict__ outA)
{
  constexpr int PASSES = 4, MAXP = 2;
  __shared__ __align__(16) char smem[2 * 4096];

  const int tid = threadIdx.x;
  const int lane = tid & 63;
  const int col = lane & 15;
  const int quad = lane >> 4;
  const int w = tid >> 6;            // = mw (3 waves)
  const int pix0 = blockIdx.x * 64;

  const signed char* bptr[MAXP];
  #pragma unroll
  for (int k = 0; k < MAXP; k++) {
    int p = w + k * 3;
    if (p >= PASSES) break;
    bptr[k] = patch + (size_t)(pix0 + p * 16 + col) * 128 + quad * 16;
  }

  // A: load all 8 frags (2 ch-steps x 4 mf) once
  i32x4 afr[2][4];
  #pragma unroll
  for (int ch = 0; ch < 2; ch++)
    #pragma unroll
    for (int i = 0; i < 4; i++)
      afr[ch][i] = *(const i32x4*)(wq + ch * 12288 + (w * 4 + i) * 1024 + lane * 16);

  i32x4 acc[4][4];
  #pragma unroll
  for (int fm = 0; fm < 4; fm++)
    #pragma unroll
    for (int fn = 0; fn < 4; fn++) acc[fm][fn] = (i32x4){0, 0, 0, 0};

  // preload step0 B into buf0
  #pragma unroll
  for (int k = 0; k < MAXP; k++) {
    int p = w + k * 3;
    if (p >= PASSES) break;
    load_lds16(bptr[k], smem + p * 1024);
  }

  #pragma unroll 1
  for (int ch = 0; ch < 2; ch++) {
    __syncthreads();                 // buf[ch] staged & drained
    if (ch == 0) {
      #pragma unroll
      for (int k = 0; k < MAXP; k++) {
        int p = w + k * 3;
        if (p >= PASSES) break;
        load_lds16(bptr[k] + 64, smem + 4096 + p * 1024);
      }
    }
    const char* pB = smem + ch * 4096 + lane * 16;
    i32x4 bfr[4];
    #pragma unroll
    for (int i = 0; i < 4; i++) bfr[i] = *(const i32x4*)(pB + i * 1024);
    #pragma unroll
    for (int fm = 0; fm < 4; fm++)
      #pragma unroll
      for (int fn = 0; fn < 4; fn++)
        acc[fm][fn] = __builtin_amdgcn_mfma_i32_16x16x64_i8(
            afr[ch][fm], bfr[fn], acc[fm][fn], 0, 0, 0);
  }

  // epilogue: layer0 scaling — bias*256, sh = md0
  const int rl = reluP[0];
  const int sh = mdP[0];
  const ll clpv = llrint(255.0 / (double)rl * 16777216.0);
  const ll sclv = (ll)((rl + 4) >> 3);
  #pragma unroll
  for (int fm = 0; fm < 4; fm++) {
    const int oc0 = w * 64 + fm * 16 + quad * 4;
    ll bi[4], mu[4];
    #pragma unroll
    for (int r = 0; r < 4; r++) {
      bi[r] = llrintf(bias[oc0 + r] * 256.0f) + 128LL * totw[oc0 + r];
      mu[r] = llrintf(mulv[oc0 + r]);
    }
    #pragma unroll
    for (int fn = 0; fn < 4; fn++) {
      const int pix = pix0 + fn * 16 + col;
      u32 wd = 0;
      #pragma unroll
      for (int r = 0; r < 4; r++) {
        ll vi = ((ll)acc[fm][fn][r] + bi[r]) * mu[r];
        ll y = (vi + (1LL << (sh - 1))) >> sh;
        y = y < 0 ? 0LL : (y > clpv ? clpv : y);
        y = (y * sclv + (1LL << 20)) >> 21;      // [0,255]
        wd |= (((u32)y ^ 0x80u) & 0xFFu) << (8 * r);
      }
      *(u32*)(outA + (size_t)pix * 192 + oc0) = wd;
    }
  }
}

// ---------------------------------------------------------------------------
// Layers 1-3: implicit GEMM, mfma_i32_16x16x64_i8.
// ONE barrier per TAP (K=192): B for tap t+1 staged into the other 12KB LDS
// buffer right after the barrier of tap t, flying under 48 MFMA of compute.
// A-frags register-rotated one ch-chunk ahead (global, L2-resident).
// Block = MW waves: 64 pix, full-COUT.
// ---------------------------------------------------------------------------
template <int COUT, int HIN, int WIN, int HOUT, int WOUT, int MW,
          int KSPLIT, bool DIRECT>
__global__ __launch_bounds__(MW * 64, 3) void convS(
    const signed char* __restrict__ act, const signed char* __restrict__ wp,
    const float* __restrict__ bias, const float* __restrict__ mulv,
    const int* __restrict__ totw,
    const int* __restrict__ reluP, const int* __restrict__ mdP,
    const signed char* __restrict__ zbuf,
    unsigned char* __restrict__ outA, int* __restrict__ outP)
{
  constexpr int CIN = 192;
  constexpr int PASSES = 12;             // B passes per tap (1KB each): 3ch x 4fn
  constexpr int MAXP = (PASSES + MW - 1) / MW;
  constexpr int SAe = MW * 4096;         // A bytes per ch-chunk: M x 64ci
  constexpr int TX = WOUT / 16;
  constexpr int TYB = HOUT / 4;
  constexpr int TPP = 25 / KSPLIT;
  constexpr int PSZ = 4 * HOUT * WOUT * COUT;
  static_assert(MW * 64 == COUT, "M covers COUT");

  __shared__ __align__(16) char smem[2 * 12288];

  const int tid = threadIdx.x;
  const int lane = tid & 63;
  const int col = lane & 15;
  const int quad = lane >> 4;
  const int w = tid >> 6;                // = mw
  const int part = blockIdx.y;

  int bx = blockIdx.x;
  const int tx = bx % TX; bx /= TX;
  const int ty = bx % TYB;
  const int b = bx / TYB;
  const int ox0 = tx * 16;
  const int oy0 = ty * 4;

  // ---- B row pointers / pad masks, indexed by fn (static across taps) ----
  const signed char* bptr[4];
  int bmx[4], bmy[4];
  #pragma unroll
  for (int fn = 0; fn < 4; fn++) {
    int oxv = ox0 + col;
    int oyv = oy0 + fn;
    bptr[fn] = act + ((size_t)b * HIN * WIN + (size_t)(2 * oyv) * WIN + 2 * oxv) * CIN
               + quad * 16;
    int mx = 0, my = 0;
    #pragma unroll
    for (int kk = 0; kk < 5; kk++) {
      if ((unsigned)(2 * oxv + kk - 2) < (unsigned)WIN) mx |= 1 << kk;
      if ((unsigned)(2 * oyv + kk - 2) < (unsigned)HIN) my |= 1 << kk;
    }
    bmx[fn] = mx; bmy[fn] = my;
  }

  auto stageTap = [&](int tap, int sel) {
    const int ky = tap / 5, kx = tap % 5;
    const int offT = ((ky - 2) * WIN + (kx - 2)) * CIN;
    #pragma unroll
    for (int k = 0; k < MAXP; k++) {
      int p = w + k * MW;
      if (p >= PASSES) break;
      int ch = p >> 2, fn = p & 3;
      bool v = ((bmx[fn] >> kx) & 1) && ((bmy[fn] >> ky) & 1);
      const signed char* g = v ? (bptr[fn] + offT + ch * 64) : (zbuf + quad * 16);
      load_lds16(g, smem + sel * 12288 + p * 1024);
    }
  };

  i32x4 acc[4][4];
  #pragma unroll
  for (int fm = 0; fm < 4; fm++)
    #pragma unroll
    for (int fn = 0; fn < 4; fn++) acc[fm][fn] = (i32x4){0, 0, 0, 0};

  // ---- preload: B tap0 -> buf0 ; A chunk s0 -> regs ----
  const int tap0 = part * TPP;
  const int s0 = tap0 * 3;
  const int sEnd = s0 + TPP * 3;
  stageTap(tap0, 0);
  const signed char* abase = wp + w * 4096 + lane * 16;
  i32x4 afn[4];
  #pragma unroll
  for (int i = 0; i < 4; i++)
    afn[i] = *(const i32x4*)(abase + (size_t)s0 * SAe + i * 1024);

  // ---- K loop: one barrier per tap, 3 ch-chunks (48 MFMA) inside ----
  int s = s0;
  #pragma unroll 1
  for (int t = 0; t < TPP; t++) {
    __syncthreads();   // buf[t&1] staged (its vmcnt drained by barrier wait)
    if (t + 1 < TPP) stageTap(tap0 + t + 1, (t + 1) & 1);
    const char* pT = smem + (t & 1) * 12288 + lane * 16;

    #pragma unroll
    for (int ch = 0; ch < 3; ch++) {
      i32x4 afc[4];
      #pragma unroll
      for (int i = 0; i < 4; i++) afc[i] = afn[i];
      const int snext = (s + 1 < sEnd) ? s + 1 : s;
      #pragma unroll
      for (int i = 0; i < 4; i++)
        afn[i] = *(const i32x4*)(abase + (size_t)snext * SAe + i * 1024);

      i32x4 bfr[4];
      #pragma unroll
      for (int i = 0; i < 4; i++)
        bfr[i] = *(const i32x4*)(pT + ch * 4096 + i * 1024);
      #pragma unroll
      for (int fm = 0; fm < 4; fm++)
        #pragma unroll
        for (int fn = 0; fn < 4; fn++)
          acc[fm][fn] = __builtin_amdgcn_mfma_i32_16x16x64_i8(
              afc[fm], bfr[fn], acc[fm][fn], 0, 0, 0);
      s++;
    }
  }

  // ---- epilogue ----
  if constexpr (DIRECT) {
    const int rl = reluP[0];
    const int sh = mdP[0] - 8;
    const ll clpv = llrint(255.0 / (double)rl * 16777216.0);
    const ll sclv = (ll)((rl + 4) >> 3);
    #pragma unroll
    for (int fm = 0; fm < 4; fm++) {
      const int oc0 = w * 64 + fm * 16 + quad * 4;
      ll bi[4], mu[4];
      #pragma unroll
      for (int r = 0; r < 4; r++) {
        bi[r] = llrintf(bias[oc0 + r]) + 128LL * totw[oc0 + r];
        mu[r] = llrintf(mulv[oc0 + r]);
      }
      #pragma unroll
      for (int fn = 0; fn < 4; fn++) {
        const int oyv = oy0 + fn;
        const int oxv = ox0 + col;
        u32 wd = 0;
        #pragma unroll
        for (int r = 0; r < 4; r++) {
          ll vi = ((ll)acc[fm][fn][r] + bi[r]) * mu[r];
          ll y = (vi + (1LL << (sh - 1))) >> sh;
          y = y < 0 ? 0LL : (y > clpv ? clpv : y);
          y = (y * sclv + (1LL << 20)) >> 21;      // [0,255]
          wd |= (((u32)y ^ 0x80u) & 0xFFu) << (8 * r);
        }
        *(u32*)(outA + ((size_t)((b * HOUT + oyv) * WOUT + oxv)) * COUT + oc0) = wd;
      }
    }
  } else {
    int* pout = outP + (size_t)part * PSZ;
    #pragma unroll
    for (int fm = 0; fm < 4; fm++) {
      const int oc0 = w * 64 + fm * 16 + quad * 4;
      #pragma unroll
      for (int fn = 0; fn < 4; fn++) {
        const int oyv = oy0 + fn;
        const int oxv = ox0 + col;
        *(i32x4*)(pout + ((size_t)((b * HOUT + oyv) * WOUT + oxv)) * COUT + oc0) =
            acc[fm][fn];
      }
    }
  }
}

// ---------------------------------------------------------------------------
// reduce2: sum 5 L2 partials + integer epilogue -> act3 (i8, channels-last).
// ---------------------------------------------------------------------------
__global__ __launch_bounds__(256) void reduce2(
    const int* __restrict__ partP, const float* __restrict__ bias,
    const float* __restrict__ mulv, const int* __restrict__ totw,
    const int* __restrict__ reluP, const int* __restrict__ mdP,
    unsigned char* __restrict__ outA)
{
  const int gid = blockIdx.x * 256 + threadIdx.x;   // 786432
  const int PSZ4 = 4 * 64 * 64 * 192 / 4;
  const int4* pp = (const int4*)partP;
  int4 sv = pp[gid];
  #pragma unroll
  for (int p = 1; p < 5; p++) {
    int4 v = pp[(size_t)p * PSZ4 + gid];
    sv.x += v.x; sv.y += v.y; sv.z += v.z; sv.w += v.w;
  }
  int sa[4] = {sv.x, sv.y, sv.z, sv.w};
  const int oc0 = (gid * 4) % 192;
  const int rl = reluP[0];
  const int sh = mdP[0] - 8;
  const ll clpv = llrint(255.0 / (double)rl * 16777216.0);
  const ll sclv = (ll)((rl + 4) >> 3);
  u32 wd = 0;
  #pragma unroll
  for (int r = 0; r < 4; r++) {
    ll bi = llrintf(bias[oc0 + r]) + 128LL * totw[oc0 + r];
    ll mu = llrintf(mulv[oc0 + r]);
    ll vi = ((ll)sa[r] + bi) * mu;
    ll y = (vi + (1LL << (sh - 1))) >> sh;
    y = y < 0 ? 0LL : (y > clpv ? clpv : y);
    y = (y * sclv + (1LL << 20)) >> 21;
    wd |= (((u32)y ^ 0x80u) & 0xFFu) << (8 * r);
  }
  ((u32*)outA)[gid] = wd;
}

// ---------------------------------------------------------------------------
// reduce3: sum 5 L3 partials + final shift -> d_out f32 NCHW (coalesced write).
// ---------------------------------------------------------------------------
__global__ __launch_bounds__(256) void reduce3(
    const int* __restrict__ partP, const float* __restrict__ b3,
    const float* __restrict__ mul3, const int* __restrict__ totw3,
    const int* __restrict__ mdP, const int* __restrict__ gaP,
    float* __restrict__ outF)
{
  const int gid = blockIdx.x * 256 + threadIdx.x;   // 1310720
  int t = gid;
  const int ox = t & 31; t >>= 5;
  const int oy = t & 31; t >>= 5;
  const int oc = t % 320;
  const int b  = t / 320;
  const int PSZ = 4 * 32 * 32 * 320;
  const size_t src = ((size_t)((b * 32 + oy) * 32 + ox)) * 320 + oc;
  ll s = 0;
  #pragma unroll
  for (int p = 0; p < 5; p++) s += partP[(size_t)p * PSZ + src];
  const int sh = mdP[0] - gaP[0];
  const ll bi = llrintf(b3[oc]) + 128LL * totw3[oc];
  const ll mu = llrintf(mul3[oc]);
  const ll y = ((s + bi) * mu + (1LL << (sh - 1))) >> sh;
  outF[gid] = (float)y;
}

// ---------------------------------------------------------------------------
extern "C" void kernel_launch(void* const* d_in, const int* in_sizes, int n_in,
                              void* d_out, int out_size, void* d_ws, size_t ws_size,
                              hipStream_t stream)
{
  const float* x    = (const float*)d_in[0];
  const float* w0   = (const float*)d_in[1];
  const float* b0   = (const float*)d_in[2];
  const float* w1   = (const float*)d_in[3];
  const float* b1   = (const float*)d_in[4];
  const float* w2   = (const float*)d_in[5];
  const float* b2   = (const float*)d_in[6];
  const float* w3   = (const float*)d_in[7];
  const float* b3   = (const float*)d_in[8];
  const float* mul0 = (const float*)d_in[9];
  const float* mul1 = (const float*)d_in[10];
  const float* mul2 = (const float*)d_in[11];
  const float* mul3 = (const float*)d_in[12];
  const int* relu0  = (const int*)d_in[13];
  const int* relu1  = (const int*)d_in[14];
  const int* relu2  = (const int*)d_in[15];
  const int* md0    = (const int*)d_in[16];
  const int* md1    = (const int*)d_in[17];
  const int* md2    = (const int*)d_in[18];
  const int* md3    = (const int*)d_in[19];
  const int* ga     = (const int*)d_in[20];

  char* ws = (char*)d_ws;
  size_t off = 0;
  signed char* zbuf = (signed char*)(ws + off); off += 1024;
  signed char* w0q  = (signed char*)(ws + off); off += 24576;
  signed char* w1p  = (signed char*)(ws + off); off += 921600;
  signed char* w2p  = (signed char*)(ws + off); off += 921600;
  signed char* w3p  = (signed char*)(ws + off); off += 1536000;
  int*         totw1= (int*)        (ws + off); off += 192 * 4;
  int*         totw2= (int*)        (ws + off); off += 192 * 4;
  int*         totw3= (int*)        (ws + off); off += 320 * 4;
  int*         totw0= (int*)        (ws + off); off += 192 * 4;
  unsigned char* act1 = (unsigned char*)(ws + off); off += (size_t)4 * 256 * 256 * 192;
  unsigned char* act2 = (unsigned char*)(ws + off); off += (size_t)4 * 128 * 128 * 192;
  unsigned char* act3 = (unsigned char*)(ws + off); off += (size_t)4 * 64 * 64 * 192;
  int*         partl  = (int*)(ws + off); off += (size_t)5 * 4 * 64 * 64 * 192 * 4; // 62.9MB
  signed char* patch  = (signed char*)partl;  // 33.5MB alias, disjoint lifetime
  (void)ws_size; (void)in_sizes; (void)n_in; (void)out_size;

  hipMemsetAsync(totw1, 0, (192 + 192 + 320 + 192) * 4, stream);
  // fused: quantize/im2col + weight packing + weight sums
  prep_all<<<6189, 256, 0, stream>>>(x, w0, w1, w2, w3, w0q, w1p, w2p, w3p,
                                     zbuf, patch, totw0, totw1, totw2, totw3);
  // L0 patch-GEMM (M=192, N=262144, K=128) ; 4096 blocks x 3 waves
  convP<<<4096, 192, 0, stream>>>(patch, w0q, b0, mul0, totw0, relu0, md0, act1);
  // L1: 256x256 -> 128x128x192 ; 1024 blocks x 3 waves ; direct epilogue
  convS<192, 256, 256, 128, 128, 3, 1, true><<<dim3(1024, 1), 192, 0, stream>>>(
      (const signed char*)act1, w1p, b1, mul1, totw1, relu1, md1, zbuf, act2, nullptr);
  // L2: 128x128 -> 64x64x192 ; split-K 5 -> 1280 blocks ; i32 partials
  convS<192, 128, 128, 64, 64, 3, 5, false><<<dim3(256, 5), 192, 0, stream>>>(
      (const signed char*)act2, w2p, b2, mul2, totw2, relu2, md2, zbuf, nullptr, partl);
  reduce2<<<3072, 256, 0, stream>>>(partl, b2, mul2, totw2, relu2, md2, act3);
  // L3: 64x64 -> 32x32x320 ; split-K 5 -> 320 blocks ; i32 partials
  convS<320, 64, 64, 32, 32, 5, 5, false><<<dim3(64, 5), 320, 0, stream>>>(
      (const signed char*)act3, w3p, b3, mul3, totw3, nullptr, md3, zbuf, nullptr, partl);
  reduce3<<<5120, 256, 0, stream>>>(partl, b3, mul3, totw3, md3, ga, (float*)d_out);
}

// Round 8
// 391.173 us; speedup vs baseline: 1.0895x; 1.0895x over previous
//
#include <hip/hip_runtime.h>
#include <hip/hip_bf16.h>

typedef int i32x4 __attribute__((ext_vector_type(4)));
typedef unsigned int u32;
typedef long long ll;

// async 16B global->LDS copy. LDS dest = wave-uniform base + lane*16.
__device__ __forceinline__ void load_lds16(const void* g, void* l) {
  __builtin_amdgcn_global_load_lds(
      (const __attribute__((address_space(1))) u32*)g,
      (__attribute__((address_space(3))) u32*)l, 16, 0, 0);
}

// ---------------------------------------------------------------------------
// prep_all: weight-pack + weight-sums (quant/im2col now fused into conv0F).
// Grid partition: [0,2048) packing ; [2048,2093) sums.
//   w0q : i8 [ch2][mf12][quad4][col16][e16]; k=ch*64+q*16+e, k<75 ->(ci=k/25,tap=k%25)
//   wNp : i8 [tap25][ch3][mf(M/16)][quad4][col16][e16]; ci = ch*64+q*16+e
//   zbuf : 0x80 fill (B-pad reads give value-128 uniformly)
// ---------------------------------------------------------------------------
template <int MF>
__device__ __forceinline__ void pack_i8(int j, const float* wsrc, signed char* wdst) {
  int e = j & 15, col = (j >> 4) & 15, q = (j >> 8) & 3, t = j >> 10;
  int mf = t % MF; t /= MF; int ch = t % 3; int tap = t / 3;
  int oc = mf * 16 + col, ci = ch * 64 + q * 16 + e;
  wdst[j] = (signed char)(int)rintf(wsrc[(oc * 192 + ci) * 25 + tap]);
}

__global__ __launch_bounds__(256) void prep_all(
    const float* __restrict__ w0, const float* __restrict__ w1,
    const float* __restrict__ w2, const float* __restrict__ w3,
    signed char* __restrict__ w0q, signed char* __restrict__ w1p,
    signed char* __restrict__ w2p, signed char* __restrict__ w3p,
    signed char* __restrict__ zbuf,
    int* __restrict__ totw0, int* __restrict__ totw1,
    int* __restrict__ totw2, int* __restrict__ totw3)
{
  const int blk = blockIdx.x;
  const int tid = threadIdx.x;

  if (blk < 2048) {
    // ---- weight packing ----
    if (blk == 0 && tid < 128)
      ((unsigned long long*)zbuf)[tid] = 0x8080808080808080ULL;
    const int R0 = 24576;                  // layer0, K padded to 128
    const int R1 = 921600;                 // 192-oc layers
    const int R3 = 1536000;                // 320-oc layer
    const int total = R0 + 2 * R1 + R3;
    for (int i = blk * 256 + tid; i < total; i += 2048 * 256) {
      if (i < R0) {
        int e = i & 15, col = (i >> 4) & 15, q = (i >> 8) & 3, t = i >> 10;
        int mf = t % 12, ch = t / 12;
        int k = ch * 64 + q * 16 + e;
        signed char v = 0;
        if (k < 75) {
          int ci = k / 25, tap = k - ci * 25;
          v = (signed char)(int)rintf(w0[((mf * 16 + col) * 3 + ci) * 25 + tap]);
        }
        w0q[i] = v;
      } else if (i < R0 + R1) {
        pack_i8<12>(i - R0, w1, w1p);
      } else if (i < R0 + 2 * R1) {
        pack_i8<12>(i - R0 - R1, w2, w2p);
      } else {
        pack_i8<20>(i - R0 - 2 * R1, w3, w3p);
      }
    }
  } else {
    // ---- totw sums (totw* pre-zeroed by memset) ----
    int t = (blk - 2048) * 256 + tid;
    if (t < 704 * 16) {
      int oc = t >> 4, q = t & 15;
      const float* ws; int* tot; int o = oc;
      if (oc < 192)      { ws = w1; tot = totw1; }
      else if (oc < 384) { ws = w2; tot = totw2; o = oc - 192; }
      else               { ws = w3; tot = totw3; o = oc - 384; }
      const float* p = ws + (size_t)o * 4800 + q * 300;
      int s = 0;
      #pragma unroll 4
      for (int j = 0; j < 300; j++) s += (int)rintf(p[j]);
      atomicAdd(&tot[o], s);
    } else {
      int oc = t - 704 * 16;
      if (oc < 192) {
        const float* p = w0 + (size_t)oc * 75;
        int s = 0;
        #pragma unroll 5
        for (int j = 0; j < 75; j++) s += (int)rintf(p[j]);
        totw0[oc] = s;
      }
    }
  }
}

// ---------------------------------------------------------------------------
// conv0F: fused layer-0 — quantize + im2col (in LDS) + patch-GEMM + epilogue.
// Block = 64-px ox strip of one output row; 3 waves (M=192), K=128 (2 steps).
// Phase1: x halo (3ci x 5row x 131col) -> quantized i8 ilds (value-128).
// Phase2: build B fragment-image in LDS: [ch2*fn4][quad4][col16][e16] (8KB),
//         the exact frag*1024 + lane*16 layout (bank-uniform ds_read_b128).
// Phase3: A-frags from w0q (global, L2-hot), 32 MFMA/wave, integer epilogue.
// ---------------------------------------------------------------------------
__global__ __launch_bounds__(192, 3) void conv0F(
    const float* __restrict__ x, const signed char* __restrict__ wq,
    const float* __restrict__ bias, const float* __restrict__ mulv,
    const int* __restrict__ totw,
    const int* __restrict__ reluP, const int* __restrict__ mdP,
    unsigned char* __restrict__ outA)
{
  __shared__ signed char ilds[3][5][132];                 // ~2KB
  __shared__ __align__(16) signed char bimg[8 * 1024];    // 8KB frag image

  const int tid = threadIdx.x;
  const int lane = tid & 63;
  const int col = lane & 15;
  const int quad = lane >> 4;
  const int w = tid >> 6;            // = mw (3 waves)
  const int blk = blockIdx.x;
  const int oxblk = blk & 3;
  const int oy = (blk >> 2) & 255;
  const int b = blk >> 10;
  const int oxbase = oxblk * 64;

  // A: issue all 8 frag loads early (they fly under phase1/2)
  i32x4 afr[2][4];
  #pragma unroll
  for (int ch = 0; ch < 2; ch++)
    #pragma unroll
    for (int i = 0; i < 4; i++)
      afr[ch][i] = *(const i32x4*)(wq + ch * 12288 + (w * 4 + i) * 1024 + lane * 16);

  // ---- phase 1: quantize halo into ilds ----
  for (int i = tid; i < 3 * 5 * 131; i += 192) {
    int c = i % 131; int t = i / 131; int r = t % 5; int ci = t / 5;
    int iy = 2 * oy - 2 + r;
    int ix = 2 * oxbase - 2 + c;
    int v = -128;
    if ((unsigned)iy < 512u && (unsigned)ix < 512u) {
      float xv = rintf(x[((b * 3 + ci) * 512 + iy) * 512 + ix] * 256.0f);
      xv = fminf(fmaxf(xv, 0.0f), 255.0f);
      v = (int)xv - 128;
    }
    ilds[ci][r][c] = (signed char)v;
  }
  __syncthreads();

  // ---- phase 2: im2col into the fragment image ----
  // slot s = (px, part): px = s>>2 (0..63), part = s&3 covers k = part*32..+32.
  // dest: fn=px>>4, colp=px&15, ch=part>>1, q0=(part&1)*2 ->
  //       bimg[(ch*4+fn)*1024 + q*256 + colp*16 + e]
  for (int s = tid; s < 256; s += 192) {
    int px = s >> 2, part = s & 3;
    int xbase = 2 * px;
    u32 res[8];
    #pragma unroll
    for (int wd = 0; wd < 8; wd++) {
      u32 v = 0;
      #pragma unroll
      for (int bb = 0; bb < 4; bb++) {
        int k = part * 32 + wd * 4 + bb;
        u32 byte = 0;
        if (k < 75) {
          int ci = k / 25, rem = k - ci * 25, ky = rem / 5, kx = rem - ky * 5;
          byte = (u32)(unsigned char)ilds[ci][ky][xbase + kx];
        }
        v |= byte << (8 * bb);
      }
      res[wd] = v;
    }
    int fn = px >> 4, colp = px & 15;
    int ch = part >> 1, q0 = (part & 1) * 2;
    signed char* d0 = bimg + (ch * 4 + fn) * 1024 + q0 * 256 + colp * 16;
    *(uint4*)d0         = make_uint4(res[0], res[1], res[2], res[3]);
    *(uint4*)(d0 + 256) = make_uint4(res[4], res[5], res[6], res[7]);
  }
  __syncthreads();

  // ---- phase 3: MFMA ----
  i32x4 acc[4][4];
  #pragma unroll
  for (int fm = 0; fm < 4; fm++)
    #pragma unroll
    for (int fn = 0; fn < 4; fn++) acc[fm][fn] = (i32x4){0, 0, 0, 0};

  #pragma unroll
  for (int ch = 0; ch < 2; ch++) {
    i32x4 bfr[4];
    #pragma unroll
    for (int fn = 0; fn < 4; fn++)
      bfr[fn] = *(const i32x4*)(bimg + (ch * 4 + fn) * 1024 + lane * 16);
    #pragma unroll
    for (int fm = 0; fm < 4; fm++)
      #pragma unroll
      for (int fn = 0; fn < 4; fn++)
        acc[fm][fn] = __builtin_amdgcn_mfma_i32_16x16x64_i8(
            afr[ch][fm], bfr[fn], acc[fm][fn], 0, 0, 0);
  }

  // ---- epilogue: layer0 scaling — bias*256, sh = md0 ----
  const size_t pix0 = ((size_t)(b * 256 + oy)) * 256 + oxbase;
  const int rl = reluP[0];
  const int sh = mdP[0];
  const ll clpv = llrint(255.0 / (double)rl * 16777216.0);
  const ll sclv = (ll)((rl + 4) >> 3);
  #pragma unroll
  for (int fm = 0; fm < 4; fm++) {
    const int oc0 = w * 64 + fm * 16 + quad * 4;
    ll bi[4], mu[4];
    #pragma unroll
    for (int r = 0; r < 4; r++) {
      bi[r] = llrintf(bias[oc0 + r] * 256.0f) + 128LL * totw[oc0 + r];
      mu[r] = llrintf(mulv[oc0 + r]);
    }
    #pragma unroll
    for (int fn = 0; fn < 4; fn++) {
      const size_t pix = pix0 + fn * 16 + col;
      u32 wd = 0;
      #pragma unroll
      for (int r = 0; r < 4; r++) {
        ll vi = ((ll)acc[fm][fn][r] + bi[r]) * mu[r];
        ll y = (vi + (1LL << (sh - 1))) >> sh;
        y = y < 0 ? 0LL : (y > clpv ? clpv : y);
        y = (y * sclv + (1LL << 20)) >> 21;      // [0,255]
        wd |= (((u32)y ^ 0x80u) & 0xFFu) << (8 * r);
      }
      *(u32*)(outA + pix * 192 + oc0) = wd;
    }
  }
}

// ---------------------------------------------------------------------------
// Layers 1-3: implicit GEMM, mfma_i32_16x16x64_i8, SINGLE barrier per K-step
// (the R6-proven structure). B double-buffered in LDS: stage step s+1 into
// buf[(s+1)&1] right after the barrier of step s. A-frags register-rotated.
// Block = MW waves: 64 pix, full-COUT.
// ---------------------------------------------------------------------------
template <int COUT, int HIN, int WIN, int HOUT, int WOUT, int MW,
          int KSPLIT, bool DIRECT>
__global__ __launch_bounds__(MW * 64, 3) void convS(
    const signed char* __restrict__ act, const signed char* __restrict__ wp,
    const float* __restrict__ bias, const float* __restrict__ mulv,
    const int* __restrict__ totw,
    const int* __restrict__ reluP, const int* __restrict__ mdP,
    const signed char* __restrict__ zbuf,
    unsigned char* __restrict__ outA, int* __restrict__ outP)
{
  constexpr int CIN = 192;
  constexpr int PASSES = 4;              // B staging passes (1KB each)
  constexpr int MAXP = (PASSES + MW - 1) / MW;
  constexpr int SAe = MW * 4096;         // A bytes per step: M x 64ci
  constexpr int TX = WOUT / 16;
  constexpr int TYB = HOUT / 4;
  constexpr int TPP = 25 / KSPLIT;
  constexpr int NSTEP = TPP * 3;
  constexpr int PSZ = 4 * HOUT * WOUT * COUT;
  static_assert(MW * 64 == COUT, "M covers COUT");

  __shared__ __align__(16) char smem[2 * 4096];

  const int tid = threadIdx.x;
  const int lane = tid & 63;
  const int col = lane & 15;
  const int quad = lane >> 4;
  const int w = tid >> 6;                // = mw
  const int part = blockIdx.y;

  int bx = blockIdx.x;
  const int tx = bx % TX; bx /= TX;
  const int ty = bx % TYB;
  const int b = bx / TYB;
  const int ox0 = tx * 16;
  const int oy0 = ty * 4;

  // ---- B-pass precompute (static across K-steps) ----
  const signed char* bptr[MAXP];
  int bmx[MAXP], bmy[MAXP];
  #pragma unroll
  for (int k = 0; k < MAXP; k++) {
    int p = w + k * MW;
    if (p >= PASSES) break;
    int oxv = ox0 + col;
    int oyv = oy0 + p;
    bptr[k] = act + ((size_t)b * HIN * WIN + (size_t)(2 * oyv) * WIN + 2 * oxv) * CIN
              + quad * 16;
    int mx = 0, my = 0;
    #pragma unroll
    for (int kk = 0; kk < 5; kk++) {
      if ((unsigned)(2 * oxv + kk - 2) < (unsigned)WIN) mx |= 1 << kk;
      if ((unsigned)(2 * oyv + kk - 2) < (unsigned)HIN) my |= 1 << kk;
    }
    bmx[k] = mx; bmy[k] = my;
  }

  auto stageStep = [&](int tap, int ch, int sel) {
    const int ky = tap / 5, kx = tap % 5;
    const int offB = ((ky - 2) * WIN + (kx - 2)) * CIN + ch * 64;
    #pragma unroll
    for (int k = 0; k < MAXP; k++) {
      int p = w + k * MW;
      if (p >= PASSES) break;
      bool v = ((bmx[k] >> kx) & 1) && ((bmy[k] >> ky) & 1);
      const signed char* g = v ? (bptr[k] + offB) : (zbuf + quad * 16);
      load_lds16(g, smem + sel * 4096 + p * 1024);
    }
  };

  i32x4 acc[4][4];
  #pragma unroll
  for (int fm = 0; fm < 4; fm++)
    #pragma unroll
    for (int fn = 0; fn < 4; fn++) acc[fm][fn] = (i32x4){0, 0, 0, 0};

  // ---- preload: B step0 -> buf0 ; A step0 -> regs ----
  const int tap0 = part * TPP;
  stageStep(tap0, 0, 0);
  const signed char* aptr = wp + (size_t)(tap0 * 3) * SAe + w * 4096 + lane * 16;
  i32x4 afn[4];
  #pragma unroll
  for (int i = 0; i < 4; i++)
    afn[i] = *(const i32x4*)(aptr + i * 1024);

  int tapN = tap0, chN = 1;              // next step to stage

  // ---- K loop: one barrier per step ----
  #pragma unroll 1
  for (int sl = 0; sl < NSTEP; sl++) {
    __syncthreads();   // buf[sl&1] staged (own vmcnt drained by barrier)

    if (sl + 1 < NSTEP) {
      stageStep(tapN, chN, (sl + 1) & 1);
      chN++;
      if (chN == 3) { chN = 0; tapN++; }
    }

    i32x4 afc[4];
    #pragma unroll
    for (int i = 0; i < 4; i++) afc[i] = afn[i];
    if (sl + 1 < NSTEP) {
      aptr += SAe;
      #pragma unroll
      for (int i = 0; i < 4; i++)
        afn[i] = *(const i32x4*)(aptr + i * 1024);
    }

    const char* pB = smem + (sl & 1) * 4096 + lane * 16;
    i32x4 bfr[4];
    #pragma unroll
    for (int i = 0; i < 4; i++)
      bfr[i] = *(const i32x4*)(pB + i * 1024);
    #pragma unroll
    for (int fm = 0; fm < 4; fm++)
      #pragma unroll
      for (int fn = 0; fn < 4; fn++)
        acc[fm][fn] = __builtin_amdgcn_mfma_i32_16x16x64_i8(
            afc[fm], bfr[fn], acc[fm][fn], 0, 0, 0);
  }

  // ---- epilogue ----
  if constexpr (DIRECT) {
    const int rl = reluP[0];
    const int sh = mdP[0] - 8;
    const ll clpv = llrint(255.0 / (double)rl * 16777216.0);
    const ll sclv = (ll)((rl + 4) >> 3);
    #pragma unroll
    for (int fm = 0; fm < 4; fm++) {
      const int oc0 = w * 64 + fm * 16 + quad * 4;
      ll bi[4], mu[4];
      #pragma unroll
      for (int r = 0; r < 4; r++) {
        bi[r] = llrintf(bias[oc0 + r]) + 128LL * totw[oc0 + r];
        mu[r] = llrintf(mulv[oc0 + r]);
      }
      #pragma unroll
      for (int fn = 0; fn < 4; fn++) {
        const int oyv = oy0 + fn;
        const int oxv = ox0 + col;
        u32 wd = 0;
        #pragma unroll
        for (int r = 0; r < 4; r++) {
          ll vi = ((ll)acc[fm][fn][r] + bi[r]) * mu[r];
          ll y = (vi + (1LL << (sh - 1))) >> sh;
          y = y < 0 ? 0LL : (y > clpv ? clpv : y);
          y = (y * sclv + (1LL << 20)) >> 21;      // [0,255]
          wd |= (((u32)y ^ 0x80u) & 0xFFu) << (8 * r);
        }
        *(u32*)(outA + ((size_t)((b * HOUT + oyv) * WOUT + oxv)) * COUT + oc0) = wd;
      }
    }
  } else {
    int* pout = outP + (size_t)part * PSZ;
    #pragma unroll
    for (int fm = 0; fm < 4; fm++) {
      const int oc0 = w * 64 + fm * 16 + quad * 4;
      #pragma unroll
      for (int fn = 0; fn < 4; fn++) {
        const int oyv = oy0 + fn;
        const int oxv = ox0 + col;
        *(i32x4*)(pout + ((size_t)((b * HOUT + oyv) * WOUT + oxv)) * COUT + oc0) =
            acc[fm][fn];
      }
    }
  }
}

// ---------------------------------------------------------------------------
// reduce2: sum 5 L2 partials + integer epilogue -> act3 (i8, channels-last).
// ---------------------------------------------------------------------------
__global__ __launch_bounds__(256) void reduce2(
    const int* __restrict__ partP, const float* __restrict__ bias,
    const float* __restrict__ mulv, const int* __restrict__ totw,
    const int* __restrict__ reluP, const int* __restrict__ mdP,
    unsigned char* __restrict__ outA)
{
  const int gid = blockIdx.x * 256 + threadIdx.x;   // 786432
  const int PSZ4 = 4 * 64 * 64 * 192 / 4;
  const int4* pp = (const int4*)partP;
  int4 sv = pp[gid];
  #pragma unroll
  for (int p = 1; p < 5; p++) {
    int4 v = pp[(size_t)p * PSZ4 + gid];
    sv.x += v.x; sv.y += v.y; sv.z += v.z; sv.w += v.w;
  }
  int sa[4] = {sv.x, sv.y, sv.z, sv.w};
  const int oc0 = (gid * 4) % 192;
  const int rl = reluP[0];
  const int sh = mdP[0] - 8;
  const ll clpv = llrint(255.0 / (double)rl * 16777216.0);
  const ll sclv = (ll)((rl + 4) >> 3);
  u32 wd = 0;
  #pragma unroll
  for (int r = 0; r < 4; r++) {
    ll bi = llrintf(bias[oc0 + r]) + 128LL * totw[oc0 + r];
    ll mu = llrintf(mulv[oc0 + r]);
    ll vi = ((ll)sa[r] + bi) * mu;
    ll y = (vi + (1LL << (sh - 1))) >> sh;
    y = y < 0 ? 0LL : (y > clpv ? clpv : y);
    y = (y * sclv + (1LL << 20)) >> 21;
    wd |= (((u32)y ^ 0x80u) & 0xFFu) << (8 * r);
  }
  ((u32*)outA)[gid] = wd;
}

// ---------------------------------------------------------------------------
// reduce3: sum 5 L3 partials + final shift -> d_out f32 NCHW (coalesced write).
// ---------------------------------------------------------------------------
__global__ __launch_bounds__(256) void reduce3(
    const int* __restrict__ partP, const float* __restrict__ b3,
    const float* __restrict__ mul3, const int* __restrict__ totw3,
    const int* __restrict__ mdP, const int* __restrict__ gaP,
    float* __restrict__ outF)
{
  const int gid = blockIdx.x * 256 + threadIdx.x;   // 1310720
  int t = gid;
  const int ox = t & 31; t >>= 5;
  const int oy = t & 31; t >>= 5;
  const int oc = t % 320;
  const int b  = t / 320;
  const int PSZ = 4 * 32 * 32 * 320;
  const size_t src = ((size_t)((b * 32 + oy) * 32 + ox)) * 320 + oc;
  ll s = 0;
  #pragma unroll
  for (int p = 0; p < 5; p++) s += partP[(size_t)p * PSZ + src];
  const int sh = mdP[0] - gaP[0];
  const ll bi = llrintf(b3[oc]) + 128LL * totw3[oc];
  const ll mu = llrintf(mul3[oc]);
  const ll y = ((s + bi) * mu + (1LL << (sh - 1))) >> sh;
  outF[gid] = (float)y;
}

// ---------------------------------------------------------------------------
extern "C" void kernel_launch(void* const* d_in, const int* in_sizes, int n_in,
                              void* d_out, int out_size, void* d_ws, size_t ws_size,
                              hipStream_t stream)
{
  const float* x    = (const float*)d_in[0];
  const float* w0   = (const float*)d_in[1];
  const float* b0   = (const float*)d_in[2];
  const float* w1   = (const float*)d_in[3];
  const float* b1   = (const float*)d_in[4];
  const float* w2   = (const float*)d_in[5];
  const float* b2   = (const float*)d_in[6];
  const float* w3   = (const float*)d_in[7];
  const float* b3   = (const float*)d_in[8];
  const float* mul0 = (const float*)d_in[9];
  const float* mul1 = (const float*)d_in[10];
  const float* mul2 = (const float*)d_in[11];
  const float* mul3 = (const float*)d_in[12];
  const int* relu0  = (const int*)d_in[13];
  const int* relu1  = (const int*)d_in[14];
  const int* relu2  = (const int*)d_in[15];
  const int* md0    = (const int*)d_in[16];
  const int* md1    = (const int*)d_in[17];
  const int* md2    = (const int*)d_in[18];
  const int* md3    = (const int*)d_in[19];
  const int* ga     = (const int*)d_in[20];

  char* ws = (char*)d_ws;
  size_t off = 0;
  signed char* zbuf = (signed char*)(ws + off); off += 1024;
  signed char* w0q  = (signed char*)(ws + off); off += 24576;
  signed char* w1p  = (signed char*)(ws + off); off += 921600;
  signed char* w2p  = (signed char*)(ws + off); off += 921600;
  signed char* w3p  = (signed char*)(ws + off); off += 1536000;
  int*         totw1= (int*)        (ws + off); off += 192 * 4;
  int*         totw2= (int*)        (ws + off); off += 192 * 4;
  int*         totw3= (int*)        (ws + off); off += 320 * 4;
  int*         totw0= (int*)        (ws + off); off += 192 * 4;
  unsigned char* act1 = (unsigned char*)(ws + off); off += (size_t)4 * 256 * 256 * 192;
  unsigned char* act2 = (unsigned char*)(ws + off); off += (size_t)4 * 128 * 128 * 192;
  unsigned char* act3 = (unsigned char*)(ws + off); off += (size_t)4 * 64 * 64 * 192;
  int*         partl  = (int*)(ws + off); off += (size_t)5 * 4 * 64 * 64 * 192 * 4; // 62.9MB
  (void)ws_size; (void)in_sizes; (void)n_in; (void)out_size;

  hipMemsetAsync(totw1, 0, (192 + 192 + 320 + 192) * 4, stream);
  // weight packing + weight sums
  prep_all<<<2093, 256, 0, stream>>>(w0, w1, w2, w3, w0q, w1p, w2p, w3p,
                                     zbuf, totw0, totw1, totw2, totw3);
  // L0 fused: quantize + im2col(LDS) + GEMM (M=192, N=262144, K=128)
  conv0F<<<4096, 192, 0, stream>>>(x, w0q, b0, mul0, totw0, relu0, md0, act1);
  // L1: 256x256 -> 128x128x192 ; 1024 blocks x 3 waves ; direct epilogue
  convS<192, 256, 256, 128, 128, 3, 1, true><<<dim3(1024, 1), 192, 0, stream>>>(
      (const signed char*)act1, w1p, b1, mul1, totw1, relu1, md1, zbuf, act2, nullptr);
  // L2: 128x128 -> 64x64x192 ; split-K 5 -> 1280 blocks ; i32 partials
  convS<192, 128, 128, 64, 64, 3, 5, false><<<dim3(256, 5), 192, 0, stream>>>(
      (const signed char*)act2, w2p, b2, mul2, totw2, relu2, md2, zbuf, nullptr, partl);
  reduce2<<<3072, 256, 0, stream>>>(partl, b2, mul2, totw2, relu2, md2, act3);
  // L3: 64x64 -> 32x32x320 ; split-K 5 -> 320 blocks ; i32 partials
  convS<320, 64, 64, 32, 32, 5, 5, false><<<dim3(64, 5), 320, 0, stream>>>(
      (const signed char*)act3, w3p, b3, mul3, totw3, nullptr, md3, zbuf, nullptr, partl);
  reduce3<<<5120, 256, 0, stream>>>(partl, b3, mul3, totw3, md3, ga, (float*)d_out);
}

// Round 9
// 351.185 us; speedup vs baseline: 1.2135x; 1.1139x over previous
//
#include <hip/hip_runtime.h>
#include <hip/hip_bf16.h>

typedef int i32x4 __attribute__((ext_vector_type(4)));
typedef unsigned int u32;
typedef unsigned long long u64;
typedef long long ll;

// async 16B global->LDS copy. LDS dest = wave-uniform base + lane*16.
__device__ __forceinline__ void load_lds16(const void* g, void* l) {
  __builtin_amdgcn_global_load_lds(
      (const __attribute__((address_space(1))) u32*)g,
      (__attribute__((address_space(3))) u32*)l, 16, 0, 0);
}

// ---------------------------------------------------------------------------
// prep_all: weight-pack + weight-sums.
// Grid partition: [0,2048) packing ; [2048,2093) sums.
//   w0q : i8 [ch2][mf12][q4][colA16][e16] with CUSTOM k-order:
//         ch0: ky=q, ci=e/5, kx=e%5 (e<15); ch1: q==0 -> ky=4; all else 0.
//   wNp : i8 [tap25][ch3][mf(M/16)][quad4][col16][e16]; ci = ch*64+q*16+e
//   zbuf : 0x80 fill (B-pad reads give value-128 uniformly)
// ---------------------------------------------------------------------------
template <int MF>
__device__ __forceinline__ void pack_i8(int j, const float* wsrc, signed char* wdst) {
  int e = j & 15, col = (j >> 4) & 15, q = (j >> 8) & 3, t = j >> 10;
  int mf = t % MF; t /= MF; int ch = t % 3; int tap = t / 3;
  int oc = mf * 16 + col, ci = ch * 64 + q * 16 + e;
  wdst[j] = (signed char)(int)rintf(wsrc[(oc * 192 + ci) * 25 + tap]);
}

__global__ __launch_bounds__(256) void prep_all(
    const float* __restrict__ w0, const float* __restrict__ w1,
    const float* __restrict__ w2, const float* __restrict__ w3,
    signed char* __restrict__ w0q, signed char* __restrict__ w1p,
    signed char* __restrict__ w2p, signed char* __restrict__ w3p,
    signed char* __restrict__ zbuf,
    int* __restrict__ totw0, int* __restrict__ totw1,
    int* __restrict__ totw2, int* __restrict__ totw3)
{
  const int blk = blockIdx.x;
  const int tid = threadIdx.x;

  if (blk < 2048) {
    // ---- weight packing ----
    if (blk == 0 && tid < 128)
      ((unsigned long long*)zbuf)[tid] = 0x8080808080808080ULL;
    const int R0 = 24576;                  // layer0, K padded to 128
    const int R1 = 921600;                 // 192-oc layers
    const int R3 = 1536000;                // 320-oc layer
    const int total = R0 + 2 * R1 + R3;
    for (int i = blk * 256 + tid; i < total; i += 2048 * 256) {
      if (i < R0) {
        int e = i & 15, colA = (i >> 4) & 15, q = (i >> 8) & 3, t = i >> 10;
        int mf = t % 12, ch = t / 12;
        signed char v = 0;
        if (e < 15 && (ch == 0 || q == 0)) {
          int ky = (ch == 0) ? q : 4;
          int ci = e / 5, kx = e - ci * 5;
          v = (signed char)(int)rintf(
              w0[((mf * 16 + colA) * 3 + ci) * 25 + ky * 5 + kx]);
        }
        w0q[i] = v;
      } else if (i < R0 + R1) {
        pack_i8<12>(i - R0, w1, w1p);
      } else if (i < R0 + 2 * R1) {
        pack_i8<12>(i - R0 - R1, w2, w2p);
      } else {
        pack_i8<20>(i - R0 - 2 * R1, w3, w3p);
      }
    }
  } else {
    // ---- totw sums (totw* pre-zeroed by memset) ----
    int t = (blk - 2048) * 256 + tid;
    if (t < 704 * 16) {
      int oc = t >> 4, q = t & 15;
      const float* ws; int* tot; int o = oc;
      if (oc < 192)      { ws = w1; tot = totw1; }
      else if (oc < 384) { ws = w2; tot = totw2; o = oc - 192; }
      else               { ws = w3; tot = totw3; o = oc - 384; }
      const float* p = ws + (size_t)o * 4800 + q * 300;
      int s = 0;
      #pragma unroll 4
      for (int j = 0; j < 300; j++) s += (int)rintf(p[j]);
      atomicAdd(&tot[o], s);
    } else {
      int oc = t - 704 * 16;
      if (oc < 192) {
        const float* p = w0 + (size_t)oc * 75;
        int s = 0;
        #pragma unroll 5
        for (int j = 0; j < 75; j++) s += (int)rintf(p[j]);
        totw0[oc] = s;
      }
    }
  }
}

// ---------------------------------------------------------------------------
// conv0F: fused layer-0. Block = 64-px ox strip, 3 waves (M=192), K=128.
// Phase1: halo (3ci x 5row x 131col) quantized into ilds (value-128), float2
//         global loads + u16 LDS writes.
// Phase2: B fragments built IN REGISTERS per lane from 3 contiguous 5-byte
//         row windows (custom k-order; A=0 slots make pad bytes don't-care).
// Phase3: 32 MFMA/wave + pure-i32 epilogue (layer-0 ranges fit i32).
// ---------------------------------------------------------------------------
__global__ __launch_bounds__(192, 3) void conv0F(
    const float* __restrict__ x, const signed char* __restrict__ wq,
    const float* __restrict__ bias, const float* __restrict__ mulv,
    const int* __restrict__ totw,
    const int* __restrict__ reluP, const int* __restrict__ mdP,
    unsigned char* __restrict__ outA)
{
  __shared__ signed char ilds[3][5][132];   // ~2KB; [ci][row][c], c=ix-(2oxbase-2)

  const int tid = threadIdx.x;
  const int lane = tid & 63;
  const int col = lane & 15;
  const int quad = lane >> 4;
  const int w = tid >> 6;            // = mw (3 waves)
  const int blk = blockIdx.x;
  const int oxblk = blk & 3;
  const int oy = (blk >> 2) & 255;
  const int b = blk >> 10;
  const int oxbase = oxblk * 64;

  // A-frags: issue early, fly under phase 1 (w0q layout matches custom k-order)
  i32x4 afr[2][4];
  #pragma unroll
  for (int ch = 0; ch < 2; ch++)
    #pragma unroll
    for (int i = 0; i < 4; i++)
      afr[ch][i] = *(const i32x4*)(wq + ch * 12288 + (w * 4 + i) * 1024 + lane * 16);

  // ---- phase 1: quantize halo into ilds (pairs; pad = -128) ----
  const float* xb = x + (size_t)b * 3 * 512 * 512;
  for (int i = tid; i < 990; i += 192) {
    int j = i % 66; int t = i / 66; int r = t % 5; int ci = t / 5;
    int iy = 2 * oy - 2 + r;
    int ix = 2 * oxbase - 2 + 2 * j;
    int v0 = -128, v1 = -128;
    if ((unsigned)iy < 512u) {
      const float* row = xb + ((size_t)ci * 512 + iy) * 512;
      if ((unsigned)ix < 512u) {
        float xv = rintf(row[ix] * 256.0f);
        v0 = (int)fminf(fmaxf(xv, 0.0f), 255.0f) - 128;
      }
      if ((unsigned)(ix + 1) < 512u) {
        float xv = rintf(row[ix + 1] * 256.0f);
        v1 = (int)fminf(fmaxf(xv, 0.0f), 255.0f) - 128;
      }
    }
    *(unsigned short*)&ilds[ci][r][2 * j] =
        (unsigned short)((v0 & 0xFF) | ((v1 & 0xFF) << 8));
  }
  __syncthreads();

  // ---- phase 2+3: per-fn in-register B build + MFMA ----
  i32x4 acc[4][4];
  #pragma unroll
  for (int fm = 0; fm < 4; fm++)
    #pragma unroll
    for (int fn = 0; fn < 4; fn++) acc[fm][fn] = (i32x4){0, 0, 0, 0};

  #pragma unroll
  for (int ch = 0; ch < 2; ch++) {
    const int row = (ch == 0) ? quad : 4;
    i32x4 bfr[4];
    #pragma unroll
    for (int fn = 0; fn < 4; fn++) {
      const int xb2 = 2 * (fn * 16 + col);
      const int o8 = (xb2 & 3) * 8;
      const int ab = xb2 & ~3;
      u64 w0_, w1_, w2_;
      {
        const u32* p0 = (const u32*)&ilds[0][row][ab];
        const u32* p1 = (const u32*)&ilds[1][row][ab];
        const u32* p2 = (const u32*)&ilds[2][row][ab];
        w0_ = (u64)p0[0] | ((u64)p0[1] << 32);
        w1_ = (u64)p1[0] | ((u64)p1[1] << 32);
        w2_ = (u64)p2[0] | ((u64)p2[1] << 32);
      }
      // frag bytes: [ci0 c..c+4][ci1 c..c+4][ci2 c..c+4][dc] ; c = xb2
      u32 a0 = (u32)(w0_ >> o8);
      u32 a1 = ((u32)(w0_ >> (o8 + 32)) & 0xFFu) | (((u32)(w1_ >> o8)) << 8);
      u32 a2 = ((u32)(w1_ >> (o8 + 24)) & 0xFFFFu) | (((u32)(w2_ >> o8)) << 16);
      u32 a3 = (u32)(w2_ >> (o8 + 16));
      bfr[fn] = (i32x4){(int)a0, (int)a1, (int)a2, (int)a3};
    }
    #pragma unroll
    for (int fm = 0; fm < 4; fm++)
      #pragma unroll
      for (int fn = 0; fn < 4; fn++)
        acc[fm][fn] = __builtin_amdgcn_mfma_i32_16x16x64_i8(
            afr[ch][fm], bfr[fn], acc[fm][fn], 0, 0, 0);
  }

  // ---- epilogue: pure i32 (layer-0 ranges fit; y*sclv <= 255*2^21) ----
  const size_t pix0 = ((size_t)(b * 256 + oy)) * 256 + oxbase;
  const int rl = reluP[0];
  const int sh = mdP[0];
  const ll clpv_ll = llrint(255.0 / (double)rl * 16777216.0);
  const int clpv = clpv_ll > 0x7FFFFFFFLL ? 0x7FFFFFFF : (int)clpv_ll;
  const int sclv = (int)((rl + 4) >> 3);
  const int rnd = 1 << (sh - 1);
  #pragma unroll
  for (int fm = 0; fm < 4; fm++) {
    const int oc0 = w * 64 + fm * 16 + quad * 4;
    int bim[4], mu32[4];
    #pragma unroll
    for (int r = 0; r < 4; r++) {
      int bi = (int)llrintf(bias[oc0 + r] * 256.0f) + 128 * totw[oc0 + r];
      mu32[r] = (int)llrintf(mulv[oc0 + r]);
      bim[r] = bi * mu32[r];
    }
    #pragma unroll
    for (int fn = 0; fn < 4; fn++) {
      const size_t pix = pix0 + fn * 16 + col;
      u32 wd = 0;
      #pragma unroll
      for (int r = 0; r < 4; r++) {
        int vi = acc[fm][fn][r] * mu32[r] + bim[r];
        int y = (vi + rnd) >> sh;
        y = y < 0 ? 0 : (y > clpv ? clpv : y);
        y = (y * sclv + (1 << 20)) >> 21;        // [0,255]
        wd |= (((u32)y ^ 0x80u) & 0xFFu) << (8 * r);
      }
      *(u32*)(outA + pix * 192 + oc0) = wd;
    }
  }
}

// ---------------------------------------------------------------------------
// Layers 1-3: implicit GEMM, mfma_i32_16x16x64_i8, SINGLE barrier per K-step
// (R6-proven). B double-buffered in LDS: stage step s+1 into buf[(s+1)&1]
// right after the barrier of step s. A-frags register-rotated.
// Block = MW waves: 64 pix, full-COUT.
// ---------------------------------------------------------------------------
template <int COUT, int HIN, int WIN, int HOUT, int WOUT, int MW,
          int KSPLIT, bool DIRECT>
__global__ __launch_bounds__(MW * 64, 3) void convS(
    const signed char* __restrict__ act, const signed char* __restrict__ wp,
    const float* __restrict__ bias, const float* __restrict__ mulv,
    const int* __restrict__ totw,
    const int* __restrict__ reluP, const int* __restrict__ mdP,
    const signed char* __restrict__ zbuf,
    unsigned char* __restrict__ outA, int* __restrict__ outP)
{
  constexpr int CIN = 192;
  constexpr int PASSES = 4;              // B staging passes (1KB each)
  constexpr int MAXP = (PASSES + MW - 1) / MW;
  constexpr int SAe = MW * 4096;         // A bytes per step: M x 64ci
  constexpr int TX = WOUT / 16;
  constexpr int TYB = HOUT / 4;
  constexpr int TPP = 25 / KSPLIT;
  constexpr int NSTEP = TPP * 3;
  constexpr int PSZ = 4 * HOUT * WOUT * COUT;
  static_assert(MW * 64 == COUT, "M covers COUT");

  __shared__ __align__(16) char smem[2 * 4096];

  const int tid = threadIdx.x;
  const int lane = tid & 63;
  const int col = lane & 15;
  const int quad = lane >> 4;
  const int w = tid >> 6;                // = mw
  const int part = blockIdx.y;

  int bx = blockIdx.x;
  const int tx = bx % TX; bx /= TX;
  const int ty = bx % TYB;
  const int b = bx / TYB;
  const int ox0 = tx * 16;
  const int oy0 = ty * 4;

  // ---- B-pass precompute (static across K-steps) ----
  const signed char* bptr[MAXP];
  int bmx[MAXP], bmy[MAXP];
  #pragma unroll
  for (int k = 0; k < MAXP; k++) {
    int p = w + k * MW;
    if (p >= PASSES) break;
    int oxv = ox0 + col;
    int oyv = oy0 + p;
    bptr[k] = act + ((size_t)b * HIN * WIN + (size_t)(2 * oyv) * WIN + 2 * oxv) * CIN
              + quad * 16;
    int mx = 0, my = 0;
    #pragma unroll
    for (int kk = 0; kk < 5; kk++) {
      if ((unsigned)(2 * oxv + kk - 2) < (unsigned)WIN) mx |= 1 << kk;
      if ((unsigned)(2 * oyv + kk - 2) < (unsigned)HIN) my |= 1 << kk;
    }
    bmx[k] = mx; bmy[k] = my;
  }

  auto stageStep = [&](int tap, int ch, int sel) {
    const int ky = tap / 5, kx = tap % 5;
    const int offB = ((ky - 2) * WIN + (kx - 2)) * CIN + ch * 64;
    #pragma unroll
    for (int k = 0; k < MAXP; k++) {
      int p = w + k * MW;
      if (p >= PASSES) break;
      bool v = ((bmx[k] >> kx) & 1) && ((bmy[k] >> ky) & 1);
      const signed char* g = v ? (bptr[k] + offB) : (zbuf + quad * 16);
      load_lds16(g, smem + sel * 4096 + p * 1024);
    }
  };

  i32x4 acc[4][4];
  #pragma unroll
  for (int fm = 0; fm < 4; fm++)
    #pragma unroll
    for (int fn = 0; fn < 4; fn++) acc[fm][fn] = (i32x4){0, 0, 0, 0};

  // ---- preload: B step0 -> buf0 ; A step0 -> regs ----
  const int tap0 = part * TPP;
  stageStep(tap0, 0, 0);
  const signed char* aptr = wp + (size_t)(tap0 * 3) * SAe + w * 4096 + lane * 16;
  i32x4 afn[4];
  #pragma unroll
  for (int i = 0; i < 4; i++)
    afn[i] = *(const i32x4*)(aptr + i * 1024);

  int tapN = tap0, chN = 1;              // next step to stage

  // ---- K loop: one barrier per step ----
  #pragma unroll 1
  for (int sl = 0; sl < NSTEP; sl++) {
    __syncthreads();   // buf[sl&1] staged (own vmcnt drained by barrier)

    if (sl + 1 < NSTEP) {
      stageStep(tapN, chN, (sl + 1) & 1);
      chN++;
      if (chN == 3) { chN = 0; tapN++; }
    }

    i32x4 afc[4];
    #pragma unroll
    for (int i = 0; i < 4; i++) afc[i] = afn[i];
    if (sl + 1 < NSTEP) {
      aptr += SAe;
      #pragma unroll
      for (int i = 0; i < 4; i++)
        afn[i] = *(const i32x4*)(aptr + i * 1024);
    }

    const char* pB = smem + (sl & 1) * 4096 + lane * 16;
    i32x4 bfr[4];
    #pragma unroll
    for (int i = 0; i < 4; i++)
      bfr[i] = *(const i32x4*)(pB + i * 1024);
    #pragma unroll
    for (int fm = 0; fm < 4; fm++)
      #pragma unroll
      for (int fn = 0; fn < 4; fn++)
        acc[fm][fn] = __builtin_amdgcn_mfma_i32_16x16x64_i8(
            afc[fm], bfr[fn], acc[fm][fn], 0, 0, 0);
  }

  // ---- epilogue ----
  if constexpr (DIRECT) {
    const int rl = reluP[0];
    const int sh = mdP[0] - 8;
    const ll clpv = llrint(255.0 / (double)rl * 16777216.0);
    const ll sclv = (ll)((rl + 4) >> 3);
    #pragma unroll
    for (int fm = 0; fm < 4; fm++) {
      const int oc0 = w * 64 + fm * 16 + quad * 4;
      ll bi[4], mu[4];
      #pragma unroll
      for (int r = 0; r < 4; r++) {
        bi[r] = llrintf(bias[oc0 + r]) + 128LL * totw[oc0 + r];
        mu[r] = llrintf(mulv[oc0 + r]);
      }
      #pragma unroll
      for (int fn = 0; fn < 4; fn++) {
        const int oyv = oy0 + fn;
        const int oxv = ox0 + col;
        u32 wd = 0;
        #pragma unroll
        for (int r = 0; r < 4; r++) {
          ll vi = ((ll)acc[fm][fn][r] + bi[r]) * mu[r];
          ll y = (vi + (1LL << (sh - 1))) >> sh;
          y = y < 0 ? 0LL : (y > clpv ? clpv : y);
          y = (y * sclv + (1LL << 20)) >> 21;      // [0,255]
          wd |= (((u32)y ^ 0x80u) & 0xFFu) << (8 * r);
        }
        *(u32*)(outA + ((size_t)((b * HOUT + oyv) * WOUT + oxv)) * COUT + oc0) = wd;
      }
    }
  } else {
    int* pout = outP + (size_t)part * PSZ;
    #pragma unroll
    for (int fm = 0; fm < 4; fm++) {
      const int oc0 = w * 64 + fm * 16 + quad * 4;
      #pragma unroll
      for (int fn = 0; fn < 4; fn++) {
        const int oyv = oy0 + fn;
        const int oxv = ox0 + col;
        *(i32x4*)(pout + ((size_t)((b * HOUT + oyv) * WOUT + oxv)) * COUT + oc0) =
            acc[fm][fn];
      }
    }
  }
}

// ---------------------------------------------------------------------------
// reduce2: sum 5 L2 partials + integer epilogue -> act3 (i8, channels-last).
// ---------------------------------------------------------------------------
__global__ __launch_bounds__(256) void reduce2(
    const int* __restrict__ partP, const float* __restrict__ bias,
    const float* __restrict__ mulv, const int* __restrict__ totw,
    const int* __restrict__ reluP, const int* __restrict__ mdP,
    unsigned char* __restrict__ outA)
{
  const int gid = blockIdx.x * 256 + threadIdx.x;   // 786432
  const int PSZ4 = 4 * 64 * 64 * 192 / 4;
  const int4* pp = (const int4*)partP;
  int4 sv = pp[gid];
  #pragma unroll
  for (int p = 1; p < 5; p++) {
    int4 v = pp[(size_t)p * PSZ4 + gid];
    sv.x += v.x; sv.y += v.y; sv.z += v.z; sv.w += v.w;
  }
  int sa[4] = {sv.x, sv.y, sv.z, sv.w};
  const int oc0 = (gid * 4) % 192;
  const int rl = reluP[0];
  const int sh = mdP[0] - 8;
  const ll clpv = llrint(255.0 / (double)rl * 16777216.0);
  const ll sclv = (ll)((rl + 4) >> 3);
  u32 wd = 0;
  #pragma unroll
  for (int r = 0; r < 4; r++) {
    ll bi = llrintf(bias[oc0 + r]) + 128LL * totw[oc0 + r];
    ll mu = llrintf(mulv[oc0 + r]);
    ll vi = ((ll)sa[r] + bi) * mu;
    ll y = (vi + (1LL << (sh - 1))) >> sh;
    y = y < 0 ? 0LL : (y > clpv ? clpv : y);
    y = (y * sclv + (1LL << 20)) >> 21;
    wd |= (((u32)y ^ 0x80u) & 0xFFu) << (8 * r);
  }
  ((u32*)outA)[gid] = wd;
}

// ---------------------------------------------------------------------------
// reduce3: sum 5 L3 partials + final shift -> d_out f32 NCHW (coalesced write).
// ---------------------------------------------------------------------------
__global__ __launch_bounds__(256) void reduce3(
    const int* __restrict__ partP, const float* __restrict__ b3,
    const float* __restrict__ mul3, const int* __restrict__ totw3,
    const int* __restrict__ mdP, const int* __restrict__ gaP,
    float* __restrict__ outF)
{
  const int gid = blockIdx.x * 256 + threadIdx.x;   // 1310720
  int t = gid;
  const int ox = t & 31; t >>= 5;
  const int oy = t & 31; t >>= 5;
  const int oc = t % 320;
  const int b  = t / 320;
  const int PSZ = 4 * 32 * 32 * 320;
  const size_t src = ((size_t)((b * 32 + oy) * 32 + ox)) * 320 + oc;
  ll s = 0;
  #pragma unroll
  for (int p = 0; p < 5; p++) s += partP[(size_t)p * PSZ + src];
  const int sh = mdP[0] - gaP[0];
  const ll bi = llrintf(b3[oc]) + 128LL * totw3[oc];
  const ll mu = llrintf(mul3[oc]);
  const ll y = ((s + bi) * mu + (1LL << (sh - 1))) >> sh;
  outF[gid] = (float)y;
}

// ---------------------------------------------------------------------------
extern "C" void kernel_launch(void* const* d_in, const int* in_sizes, int n_in,
                              void* d_out, int out_size, void* d_ws, size_t ws_size,
                              hipStream_t stream)
{
  const float* x    = (const float*)d_in[0];
  const float* w0   = (const float*)d_in[1];
  const float* b0   = (const float*)d_in[2];
  const float* w1   = (const float*)d_in[3];
  const float* b1   = (const float*)d_in[4];
  const float* w2   = (const float*)d_in[5];
  const float* b2   = (const float*)d_in[6];
  const float* w3   = (const float*)d_in[7];
  const float* b3   = (const float*)d_in[8];
  const float* mul0 = (const float*)d_in[9];
  const float* mul1 = (const float*)d_in[10];
  const float* mul2 = (const float*)d_in[11];
  const float* mul3 = (const float*)d_in[12];
  const int* relu0  = (const int*)d_in[13];
  const int* relu1  = (const int*)d_in[14];
  const int* relu2  = (const int*)d_in[15];
  const int* md0    = (const int*)d_in[16];
  const int* md1    = (const int*)d_in[17];
  const int* md2    = (const int*)d_in[18];
  const int* md3    = (const int*)d_in[19];
  const int* ga     = (const int*)d_in[20];

  char* ws = (char*)d_ws;
  size_t off = 0;
  signed char* zbuf = (signed char*)(ws + off); off += 1024;
  signed char* w0q  = (signed char*)(ws + off); off += 24576;
  signed char* w1p  = (signed char*)(ws + off); off += 921600;
  signed char* w2p  = (signed char*)(ws + off); off += 921600;
  signed char* w3p  = (signed char*)(ws + off); off += 1536000;
  int*         totw1= (int*)        (ws + off); off += 192 * 4;
  int*         totw2= (int*)        (ws + off); off += 192 * 4;
  int*         totw3= (int*)        (ws + off); off += 320 * 4;
  int*         totw0= (int*)        (ws + off); off += 192 * 4;
  unsigned char* act1 = (unsigned char*)(ws + off); off += (size_t)4 * 256 * 256 * 192;
  unsigned char* act2 = (unsigned char*)(ws + off); off += (size_t)4 * 128 * 128 * 192;
  unsigned char* act3 = (unsigned char*)(ws + off); off += (size_t)4 * 64 * 64 * 192;
  int*         partl  = (int*)(ws + off); off += (size_t)5 * 4 * 64 * 64 * 192 * 4; // 62.9MB
  (void)ws_size; (void)in_sizes; (void)n_in; (void)out_size;

  hipMemsetAsync(totw1, 0, (192 + 192 + 320 + 192) * 4, stream);
  // weight packing + weight sums
  prep_all<<<2093, 256, 0, stream>>>(w0, w1, w2, w3, w0q, w1p, w2p, w3p,
                                     zbuf, totw0, totw1, totw2, totw3);
  // L0 fused: quantize + in-register im2col + GEMM (M=192, N=262144, K=128)
  conv0F<<<4096, 192, 0, stream>>>(x, w0q, b0, mul0, totw0, relu0, md0, act1);
  // L1: 256x256 -> 128x128x192 ; 1024 blocks x 3 waves ; direct epilogue
  convS<192, 256, 256, 128, 128, 3, 1, true><<<dim3(1024, 1), 192, 0, stream>>>(
      (const signed char*)act1, w1p, b1, mul1, totw1, relu1, md1, zbuf, act2, nullptr);
  // L2: 128x128 -> 64x64x192 ; split-K 5 -> 1280 blocks ; i32 partials
  convS<192, 128, 128, 64, 64, 3, 5, false><<<dim3(256, 5), 192, 0, stream>>>(
      (const signed char*)act2, w2p, b2, mul2, totw2, relu2, md2, zbuf, nullptr, partl);
  reduce2<<<3072, 256, 0, stream>>>(partl, b2, mul2, totw2, relu2, md2, act3);
  // L3: 64x64 -> 32x32x320 ; split-K 5 -> 320 blocks ; i32 partials
  convS<320, 64, 64, 32, 32, 5, 5, false><<<dim3(64, 5), 320, 0, stream>>>(
      (const signed char*)act3, w3p, b3, mul3, totw3, nullptr, md3, zbuf, nullptr, partl);
  reduce3<<<5120, 256, 0, stream>>>(partl, b3, mul3, totw3, md3, ga, (float*)d_out);
}

// Round 10
// 348.509 us; speedup vs baseline: 1.2228x; 1.0077x over previous
//
#include <hip/hip_runtime.h>
#include <hip/hip_bf16.h>

typedef int i32x4 __attribute__((ext_vector_type(4)));
typedef unsigned int u32;
typedef unsigned long long u64;
typedef long long ll;

// async 16B global->LDS copy. LDS dest = wave-uniform base + lane*16.
__device__ __forceinline__ void load_lds16(const void* g, void* l) {
  __builtin_amdgcn_global_load_lds(
      (const __attribute__((address_space(1))) u32*)g,
      (__attribute__((address_space(3))) u32*)l, 16, 0, 0);
}

// ---------------------------------------------------------------------------
// prep_all: weight packing via LDS transpose (coalesced reads) + totw sums.
// Grid: [0,88) transpose blocks (each owns 8 oc of one mf-half);
//       blk==88: w0q custom pack + zbuf + w0 sums.
//   wNp : i8 [s=tap*3+ch][mf(MF)][q4][col16][e16]; ci = ch*64+q*16+e
//   w0q : i8 [ch2][mf12][q4][colA16][e16], CUSTOM k-order:
//         ch0: ky=q, ci=e/5, kx=e%5 (e<15); ch1: q==0 -> ky=4; all else 0.
//   zbuf : 0x80 fill (B-pad reads give value-128 uniformly)
// ---------------------------------------------------------------------------
__global__ __launch_bounds__(256) void prep_all(
    const float* __restrict__ w0, const float* __restrict__ w1,
    const float* __restrict__ w2, const float* __restrict__ w3,
    signed char* __restrict__ w0q, signed char* __restrict__ w1p,
    signed char* __restrict__ w2p, signed char* __restrict__ w3p,
    signed char* __restrict__ zbuf,
    int* __restrict__ totw0, int* __restrict__ totw1,
    int* __restrict__ totw2, int* __restrict__ totw3)
{
  __shared__ signed char ldsw[8 * 4800];   // 38400 B
  const int blk = blockIdx.x;
  const int tid = threadIdx.x;

  if (blk < 88) {
    const float* wsrc; signed char* wdst; int* tot; int MF, sub;
    if (blk < 24)      { wsrc = w1; wdst = w1p; tot = totw1; MF = 12; sub = blk; }
    else if (blk < 48) { wsrc = w2; wdst = w2p; tot = totw2; MF = 12; sub = blk - 24; }
    else               { wsrc = w3; wdst = w3p; tot = totw3; MF = 20; sub = blk - 48; }
    const int mf = sub >> 1, half = sub & 1, colbase = half * 8;
    const int ocb = mf * 16 + colbase;
    // ---- phase A: coalesced read + quantize + per-oc sums ----
    for (int o = 0; o < 8; o++) {
      const float* src = wsrc + (size_t)(ocb + o) * 4800;
      int s = 0;
      for (int j = tid; j < 4800; j += 256) {
        int v = (int)rintf(src[j]);
        ldsw[o * 4800 + j] = (signed char)v;
        s += v;
      }
      atomicAdd(&tot[ocb + o], s);
    }
    __syncthreads();
    // ---- phase B: packed u32 writes (coalesced) ----
    for (int u = tid; u < 9600; u += 256) {
      int eu = u & 3, colL = (u >> 2) & 7, q = (u >> 5) & 3, t = u >> 7;
      int tap = t / 3, ch = t - 3 * tap;
      int ci0 = ch * 64 + q * 16 + eu * 4;
      const signed char* sp = ldsw + colL * 4800 + tap;
      u32 wv = 0;
      #pragma unroll
      for (int bb = 0; bb < 4; bb++)
        wv |= ((u32)(unsigned char)sp[(ci0 + bb) * 25]) << (8 * bb);
      *(u32*)(wdst + ((size_t)t * MF + mf) * 1024 +
              (q * 16 + colbase + colL) * 16 + eu * 4) = wv;
    }
  } else {
    // ---- blk 88: zbuf + w0q custom pack + w0 sums ----
    if (tid < 128) ((u64*)zbuf)[tid] = 0x8080808080808080ULL;
    for (int i = tid; i < 24576; i += 256) {
      int e = i & 15, colA = (i >> 4) & 15, q = (i >> 8) & 3, t = i >> 10;
      int mf = t % 12, ch = t / 12;
      signed char v = 0;
      if (e < 15 && (ch == 0 || q == 0)) {
        int ky = (ch == 0) ? q : 4;
        int ci = e / 5, kx = e - ci * 5;
        v = (signed char)(int)rintf(
            w0[((mf * 16 + colA) * 3 + ci) * 25 + ky * 5 + kx]);
      }
      w0q[i] = v;
    }
    for (int oc = tid; oc < 192; oc += 256) {
      const float* p = w0 + (size_t)oc * 75;
      int s = 0;
      #pragma unroll 5
      for (int j = 0; j < 75; j++) s += (int)rintf(p[j]);
      totw0[oc] = s;
    }
  }
}

// ---------------------------------------------------------------------------
// conv0F: fused layer-0 (unchanged from R9). Block = 64-px strip, 3 waves.
// ---------------------------------------------------------------------------
__global__ __launch_bounds__(192, 3) void conv0F(
    const float* __restrict__ x, const signed char* __restrict__ wq,
    const float* __restrict__ bias, const float* __restrict__ mulv,
    const int* __restrict__ totw,
    const int* __restrict__ reluP, const int* __restrict__ mdP,
    unsigned char* __restrict__ outA)
{
  __shared__ signed char ilds[3][5][132];

  const int tid = threadIdx.x;
  const int lane = tid & 63;
  const int col = lane & 15;
  const int quad = lane >> 4;
  const int w = tid >> 6;
  const int blk = blockIdx.x;
  const int oxblk = blk & 3;
  const int oy = (blk >> 2) & 255;
  const int b = blk >> 10;
  const int oxbase = oxblk * 64;

  i32x4 afr[2][4];
  #pragma unroll
  for (int ch = 0; ch < 2; ch++)
    #pragma unroll
    for (int i = 0; i < 4; i++)
      afr[ch][i] = *(const i32x4*)(wq + ch * 12288 + (w * 4 + i) * 1024 + lane * 16);

  const float* xb = x + (size_t)b * 3 * 512 * 512;
  for (int i = tid; i < 990; i += 192) {
    int j = i % 66; int t = i / 66; int r = t % 5; int ci = t / 5;
    int iy = 2 * oy - 2 + r;
    int ix = 2 * oxbase - 2 + 2 * j;
    int v0 = -128, v1 = -128;
    if ((unsigned)iy < 512u) {
      const float* row = xb + ((size_t)ci * 512 + iy) * 512;
      if ((unsigned)ix < 512u) {
        float xv = rintf(row[ix] * 256.0f);
        v0 = (int)fminf(fmaxf(xv, 0.0f), 255.0f) - 128;
      }
      if ((unsigned)(ix + 1) < 512u) {
        float xv = rintf(row[ix + 1] * 256.0f);
        v1 = (int)fminf(fmaxf(xv, 0.0f), 255.0f) - 128;
      }
    }
    *(unsigned short*)&ilds[ci][r][2 * j] =
        (unsigned short)((v0 & 0xFF) | ((v1 & 0xFF) << 8));
  }
  __syncthreads();

  i32x4 acc[4][4];
  #pragma unroll
  for (int fm = 0; fm < 4; fm++)
    #pragma unroll
    for (int fn = 0; fn < 4; fn++) acc[fm][fn] = (i32x4){0, 0, 0, 0};

  #pragma unroll
  for (int ch = 0; ch < 2; ch++) {
    const int row = (ch == 0) ? quad : 4;
    i32x4 bfr[4];
    #pragma unroll
    for (int fn = 0; fn < 4; fn++) {
      const int xb2 = 2 * (fn * 16 + col);
      const int o8 = (xb2 & 3) * 8;
      const int ab = xb2 & ~3;
      u64 w0_, w1_, w2_;
      {
        const u32* p0 = (const u32*)&ilds[0][row][ab];
        const u32* p1 = (const u32*)&ilds[1][row][ab];
        const u32* p2 = (const u32*)&ilds[2][row][ab];
        w0_ = (u64)p0[0] | ((u64)p0[1] << 32);
        w1_ = (u64)p1[0] | ((u64)p1[1] << 32);
        w2_ = (u64)p2[0] | ((u64)p2[1] << 32);
      }
      u32 a0 = (u32)(w0_ >> o8);
      u32 a1 = ((u32)(w0_ >> (o8 + 32)) & 0xFFu) | (((u32)(w1_ >> o8)) << 8);
      u32 a2 = ((u32)(w1_ >> (o8 + 24)) & 0xFFFFu) | (((u32)(w2_ >> o8)) << 16);
      u32 a3 = (u32)(w2_ >> (o8 + 16));
      bfr[fn] = (i32x4){(int)a0, (int)a1, (int)a2, (int)a3};
    }
    #pragma unroll
    for (int fm = 0; fm < 4; fm++)
      #pragma unroll
      for (int fn = 0; fn < 4; fn++)
        acc[fm][fn] = __builtin_amdgcn_mfma_i32_16x16x64_i8(
            afr[ch][fm], bfr[fn], acc[fm][fn], 0, 0, 0);
  }

  const size_t pix0 = ((size_t)(b * 256 + oy)) * 256 + oxbase;
  const int rl = reluP[0];
  const int sh = mdP[0];
  const ll clpv_ll = llrint(255.0 / (double)rl * 16777216.0);
  const int clpv = clpv_ll > 0x7FFFFFFFLL ? 0x7FFFFFFF : (int)clpv_ll;
  const int sclv = (int)((rl + 4) >> 3);
  const int rnd = 1 << (sh - 1);
  #pragma unroll
  for (int fm = 0; fm < 4; fm++) {
    const int oc0 = w * 64 + fm * 16 + quad * 4;
    int bim[4], mu32[4];
    #pragma unroll
    for (int r = 0; r < 4; r++) {
      int bi = (int)llrintf(bias[oc0 + r] * 256.0f) + 128 * totw[oc0 + r];
      mu32[r] = (int)llrintf(mulv[oc0 + r]);
      bim[r] = bi * mu32[r];
    }
    #pragma unroll
    for (int fn = 0; fn < 4; fn++) {
      const size_t pix = pix0 + fn * 16 + col;
      u32 wd = 0;
      #pragma unroll
      for (int r = 0; r < 4; r++) {
        int vi = acc[fm][fn][r] * mu32[r] + bim[r];
        int y = (vi + rnd) >> sh;
        y = y < 0 ? 0 : (y > clpv ? clpv : y);
        y = (y * sclv + (1 << 20)) >> 21;
        wd |= (((u32)y ^ 0x80u) & 0xFFu) << (8 * r);
      }
      *(u32*)(outA + pix * 192 + oc0) = wd;
    }
  }
}

// ---------------------------------------------------------------------------
// Layers 1-3: implicit GEMM, single barrier per K-step, UNROLLED x2 with two
// A-register banks (no per-step register copies) and incremental kx/ky/ch
// staging state (no per-step div/mod). B dbuf in LDS as in R6.
// ---------------------------------------------------------------------------
template <int COUT, int HIN, int WIN, int HOUT, int WOUT, int MW,
          int KSPLIT, bool DIRECT>
__global__ __launch_bounds__(MW * 64, 3) void convS(
    const signed char* __restrict__ act, const signed char* __restrict__ wp,
    const float* __restrict__ bias, const float* __restrict__ mulv,
    const int* __restrict__ totw,
    const int* __restrict__ reluP, const int* __restrict__ mdP,
    const signed char* __restrict__ zbuf,
    unsigned char* __restrict__ outA, int* __restrict__ outP)
{
  constexpr int CIN = 192;
  constexpr int PASSES = 4;
  constexpr int MAXP = (PASSES + MW - 1) / MW;
  constexpr int SAe = MW * 4096;
  constexpr int TX = WOUT / 16;
  constexpr int TYB = HOUT / 4;
  constexpr int TPP = 25 / KSPLIT;
  constexpr int NSTEP = TPP * 3;
  constexpr int PSZ = 4 * HOUT * WOUT * COUT;
  static_assert(MW * 64 == COUT, "M covers COUT");

  __shared__ __align__(16) char smem[2 * 4096];

  const int tid = threadIdx.x;
  const int lane = tid & 63;
  const int col = lane & 15;
  const int quad = lane >> 4;
  const int w = tid >> 6;
  const int part = blockIdx.y;

  int bx = blockIdx.x;
  const int tx = bx % TX; bx /= TX;
  const int ty = bx % TYB;
  const int b = bx / TYB;
  const int ox0 = tx * 16;
  const int oy0 = ty * 4;

  const signed char* bptr[MAXP];
  int bmx[MAXP], bmy[MAXP];
  #pragma unroll
  for (int k = 0; k < MAXP; k++) {
    int p = w + k * MW;
    if (p >= PASSES) break;
    int oxv = ox0 + col;
    int oyv = oy0 + p;
    bptr[k] = act + ((size_t)b * HIN * WIN + (size_t)(2 * oyv) * WIN + 2 * oxv) * CIN
              + quad * 16;
    int mx = 0, my = 0;
    #pragma unroll
    for (int kk = 0; kk < 5; kk++) {
      if ((unsigned)(2 * oxv + kk - 2) < (unsigned)WIN) mx |= 1 << kk;
      if ((unsigned)(2 * oyv + kk - 2) < (unsigned)HIN) my |= 1 << kk;
    }
    bmx[k] = mx; bmy[k] = my;
  }

  // staging state: (kxS, kyS, chS) of the NEXT step to stage
  int kxS, kyS, chS;

  auto stage = [&](int sel) {
    const int offB = ((kyS - 2) * WIN + (kxS - 2)) * CIN + chS * 64;
    #pragma unroll
    for (int k = 0; k < MAXP; k++) {
      int p = w + k * MW;
      if (p >= PASSES) break;
      bool v = ((bmx[k] >> kxS) & 1) && ((bmy[k] >> kyS) & 1);
      const signed char* g = v ? (bptr[k] + offB) : (zbuf + quad * 16);
      load_lds16(g, smem + sel * 4096 + p * 1024);
    }
  };
  auto adv = [&]() {
    chS++;
    if (chS == 3) { chS = 0; kxS++; if (kxS == 5) { kxS = 0; kyS++; } }
  };

  i32x4 acc[4][4];
  #pragma unroll
  for (int fm = 0; fm < 4; fm++)
    #pragma unroll
    for (int fn = 0; fn < 4; fn++) acc[fm][fn] = (i32x4){0, 0, 0, 0};

  // preload: stage step0 -> buf0 ; A(0) -> aA
  const int tap0 = part * TPP;
  kyS = tap0 / 5; kxS = tap0 - 5 * kyS; chS = 0;
  stage(0);
  adv();
  const signed char* aptr = wp + (size_t)(tap0 * 3) * SAe + w * 4096 + lane * 16;
  i32x4 aA[4], aB[4];
  #pragma unroll
  for (int i = 0; i < 4; i++) aA[i] = *(const i32x4*)(aptr + i * 1024);

  auto comp = [&](int base, i32x4 (&a)[4]) {
    const char* pB = smem + base + lane * 16;
    i32x4 bfr[4];
    #pragma unroll
    for (int i = 0; i < 4; i++)
      bfr[i] = *(const i32x4*)(pB + i * 1024);
    #pragma unroll
    for (int fm = 0; fm < 4; fm++)
      #pragma unroll
      for (int fn = 0; fn < 4; fn++)
        acc[fm][fn] = __builtin_amdgcn_mfma_i32_16x16x64_i8(
            a[fm], bfr[fn], acc[fm][fn], 0, 0, 0);
  };

  int sl = 0;
  #pragma unroll 1
  for (; sl + 1 < NSTEP; sl += 2) {
    __syncthreads();                 // buf0 (step sl) staged & drained
    stage(1); adv();                 // stage step sl+1 -> buf1
    aptr += SAe;                     // A(sl+1) -> aB
    #pragma unroll
    for (int i = 0; i < 4; i++) aB[i] = *(const i32x4*)(aptr + i * 1024);
    comp(0, aA);

    __syncthreads();                 // buf1 (step sl+1) staged & drained
    if (sl + 2 < NSTEP) {
      stage(0); adv();               // stage step sl+2 -> buf0
      aptr += SAe;                   // A(sl+2) -> aA
      #pragma unroll
      for (int i = 0; i < 4; i++) aA[i] = *(const i32x4*)(aptr + i * 1024);
    }
    comp(4096, aB);
  }
  if (sl < NSTEP) {                  // tail (NSTEP odd)
    __syncthreads();
    comp(0, aA);
  }

  // ---- epilogue ----
  if constexpr (DIRECT) {
    const int rl = reluP[0];
    const int sh = mdP[0] - 8;
    const ll clpv = llrint(255.0 / (double)rl * 16777216.0);
    const ll sclv = (ll)((rl + 4) >> 3);
    #pragma unroll
    for (int fm = 0; fm < 4; fm++) {
      const int oc0 = w * 64 + fm * 16 + quad * 4;
      ll bi[4], mu[4];
      #pragma unroll
      for (int r = 0; r < 4; r++) {
        bi[r] = llrintf(bias[oc0 + r]) + 128LL * totw[oc0 + r];
        mu[r] = llrintf(mulv[oc0 + r]);
      }
      #pragma unroll
      for (int fn = 0; fn < 4; fn++) {
        const int oyv = oy0 + fn;
        const int oxv = ox0 + col;
        u32 wd = 0;
        #pragma unroll
        for (int r = 0; r < 4; r++) {
          ll vi = ((ll)acc[fm][fn][r] + bi[r]) * mu[r];
          ll y = (vi + (1LL << (sh - 1))) >> sh;
          y = y < 0 ? 0LL : (y > clpv ? clpv : y);
          y = (y * sclv + (1LL << 20)) >> 21;
          wd |= (((u32)y ^ 0x80u) & 0xFFu) << (8 * r);
        }
        *(u32*)(outA + ((size_t)((b * HOUT + oyv) * WOUT + oxv)) * COUT + oc0) = wd;
      }
    }
  } else {
    int* pout = outP + (size_t)part * PSZ;
    #pragma unroll
    for (int fm = 0; fm < 4; fm++) {
      const int oc0 = w * 64 + fm * 16 + quad * 4;
      #pragma unroll
      for (int fn = 0; fn < 4; fn++) {
        const int oyv = oy0 + fn;
        const int oxv = ox0 + col;
        *(i32x4*)(pout + ((size_t)((b * HOUT + oyv) * WOUT + oxv)) * COUT + oc0) =
            acc[fm][fn];
      }
    }
  }
}

// ---------------------------------------------------------------------------
// reduce2: sum 5 L2 partials + integer epilogue -> act3 (i8, channels-last).
// ---------------------------------------------------------------------------
__global__ __launch_bounds__(256) void reduce2(
    const int* __restrict__ partP, const float* __restrict__ bias,
    const float* __restrict__ mulv, const int* __restrict__ totw,
    const int* __restrict__ reluP, const int* __restrict__ mdP,
    unsigned char* __restrict__ outA)
{
  const int gid = blockIdx.x * 256 + threadIdx.x;   // 786432
  const int PSZ4 = 4 * 64 * 64 * 192 / 4;
  const int4* pp = (const int4*)partP;
  int4 sv = pp[gid];
  #pragma unroll
  for (int p = 1; p < 5; p++) {
    int4 v = pp[(size_t)p * PSZ4 + gid];
    sv.x += v.x; sv.y += v.y; sv.z += v.z; sv.w += v.w;
  }
  int sa[4] = {sv.x, sv.y, sv.z, sv.w};
  const int oc0 = (gid * 4) % 192;
  const int rl = reluP[0];
  const int sh = mdP[0] - 8;
  const ll clpv = llrint(255.0 / (double)rl * 16777216.0);
  const ll sclv = (ll)((rl + 4) >> 3);
  u32 wd = 0;
  #pragma unroll
  for (int r = 0; r < 4; r++) {
    ll bi = llrintf(bias[oc0 + r]) + 128LL * totw[oc0 + r];
    ll mu = llrintf(mulv[oc0 + r]);
    ll vi = ((ll)sa[r] + bi) * mu;
    ll y = (vi + (1LL << (sh - 1))) >> sh;
    y = y < 0 ? 0LL : (y > clpv ? clpv : y);
    y = (y * sclv + (1LL << 20)) >> 21;
    wd |= (((u32)y ^ 0x80u) & 0xFFu) << (8 * r);
  }
  ((u32*)outA)[gid] = wd;
}

// ---------------------------------------------------------------------------
// reduce3: sum 5 L3 partials + final shift -> d_out f32 NCHW (coalesced write).
// ---------------------------------------------------------------------------
__global__ __launch_bounds__(256) void reduce3(
    const int* __restrict__ partP, const float* __restrict__ b3,
    const float* __restrict__ mul3, const int* __restrict__ totw3,
    const int* __restrict__ mdP, const int* __restrict__ gaP,
    float* __restrict__ outF)
{
  const int gid = blockIdx.x * 256 + threadIdx.x;   // 1310720
  int t = gid;
  const int ox = t & 31; t >>= 5;
  const int oy = t & 31; t >>= 5;
  const int oc = t % 320;
  const int b  = t / 320;
  const int PSZ = 4 * 32 * 32 * 320;
  const size_t src = ((size_t)((b * 32 + oy) * 32 + ox)) * 320 + oc;
  ll s = 0;
  #pragma unroll
  for (int p = 0; p < 5; p++) s += partP[(size_t)p * PSZ + src];
  const int sh = mdP[0] - gaP[0];
  const ll bi = llrintf(b3[oc]) + 128LL * totw3[oc];
  const ll mu = llrintf(mul3[oc]);
  const ll y = ((s + bi) * mu + (1LL << (sh - 1))) >> sh;
  outF[gid] = (float)y;
}

// ---------------------------------------------------------------------------
extern "C" void kernel_launch(void* const* d_in, const int* in_sizes, int n_in,
                              void* d_out, int out_size, void* d_ws, size_t ws_size,
                              hipStream_t stream)
{
  const float* x    = (const float*)d_in[0];
  const float* w0   = (const float*)d_in[1];
  const float* b0   = (const float*)d_in[2];
  const float* w1   = (const float*)d_in[3];
  const float* b1   = (const float*)d_in[4];
  const float* w2   = (const float*)d_in[5];
  const float* b2   = (const float*)d_in[6];
  const float* w3   = (const float*)d_in[7];
  const float* b3   = (const float*)d_in[8];
  const float* mul0 = (const float*)d_in[9];
  const float* mul1 = (const float*)d_in[10];
  const float* mul2 = (const float*)d_in[11];
  const float* mul3 = (const float*)d_in[12];
  const int* relu0  = (const int*)d_in[13];
  const int* relu1  = (const int*)d_in[14];
  const int* relu2  = (const int*)d_in[15];
  const int* md0    = (const int*)d_in[16];
  const int* md1    = (const int*)d_in[17];
  const int* md2    = (const int*)d_in[18];
  const int* md3    = (const int*)d_in[19];
  const int* ga     = (const int*)d_in[20];

  char* ws = (char*)d_ws;
  size_t off = 0;
  signed char* zbuf = (signed char*)(ws + off); off += 1024;
  signed char* w0q  = (signed char*)(ws + off); off += 24576;
  signed char* w1p  = (signed char*)(ws + off); off += 921600;
  signed char* w2p  = (signed char*)(ws + off); off += 921600;
  signed char* w3p  = (signed char*)(ws + off); off += 1536000;
  int*         totw1= (int*)        (ws + off); off += 192 * 4;
  int*         totw2= (int*)        (ws + off); off += 192 * 4;
  int*         totw3= (int*)        (ws + off); off += 320 * 4;
  int*         totw0= (int*)        (ws + off); off += 192 * 4;
  unsigned char* act1 = (unsigned char*)(ws + off); off += (size_t)4 * 256 * 256 * 192;
  unsigned char* act2 = (unsigned char*)(ws + off); off += (size_t)4 * 128 * 128 * 192;
  unsigned char* act3 = (unsigned char*)(ws + off); off += (size_t)4 * 64 * 64 * 192;
  int*         partl  = (int*)(ws + off); off += (size_t)5 * 4 * 64 * 64 * 192 * 4; // 62.9MB
  (void)ws_size; (void)in_sizes; (void)n_in; (void)out_size;

  hipMemsetAsync(totw1, 0, (192 + 192 + 320 + 192) * 4, stream);
  // weight packing (LDS transpose) + weight sums
  prep_all<<<89, 256, 0, stream>>>(w0, w1, w2, w3, w0q, w1p, w2p, w3p,
                                   zbuf, totw0, totw1, totw2, totw3);
  // L0 fused: quantize + in-register im2col + GEMM (M=192, N=262144, K=128)
  conv0F<<<4096, 192, 0, stream>>>(x, w0q, b0, mul0, totw0, relu0, md0, act1);
  // L1: 256x256 -> 128x128x192 ; 1024 blocks x 3 waves ; direct epilogue
  convS<192, 256, 256, 128, 128, 3, 1, true><<<dim3(1024, 1), 192, 0, stream>>>(
      (const signed char*)act1, w1p, b1, mul1, totw1, relu1, md1, zbuf, act2, nullptr);
  // L2: 128x128 -> 64x64x192 ; split-K 5 -> 1280 blocks ; i32 partials
  convS<192, 128, 128, 64, 64, 3, 5, false><<<dim3(256, 5), 192, 0, stream>>>(
      (const signed char*)act2, w2p, b2, mul2, totw2, relu2, md2, zbuf, nullptr, partl);
  reduce2<<<3072, 256, 0, stream>>>(partl, b2, mul2, totw2, relu2, md2, act3);
  // L3: 64x64 -> 32x32x320 ; split-K 5 -> 320 blocks ; i32 partials
  convS<320, 64, 64, 32, 32, 5, 5, false><<<dim3(64, 5), 320, 0, stream>>>(
      (const signed char*)act3, w3p, b3, mul3, totw3, nullptr, md3, zbuf, nullptr, partl);
  reduce3<<<5120, 256, 0, stream>>>(partl, b3, mul3, totw3, md3, ga, (float*)d_out);
}